// Round 1
// baseline (808.939 us; speedup 1.0000x reference)
//
#include <hip/hip_runtime.h>
#include <stdint.h>

#define T_TOKENS 2048
#define DM 1024
#define DF 4096
#define NEXP 8

typedef __bf16 bf16x8 __attribute__((ext_vector_type(8)));
typedef float f32x4 __attribute__((ext_vector_type(4)));

__device__ __forceinline__ ushort f2bf(float f) {
    union { float f; uint32_t u; } v; v.f = f;
    uint32_t r = v.u + 0x7FFFu + ((v.u >> 16) & 1u);
    return (ushort)(r >> 16);
}

// ---------------- init: zero expert counters ----------------
__global__ void init_cnt(uint32_t* cnt) {
    if (threadIdx.x < NEXP) cnt[threadIdx.x] = 0;
}

// ---------------- gating + routing: one wave per token ----------------
__global__ __launch_bounds__(256) void gate_route(
    const float* __restrict__ x, const float* __restrict__ gw,
    const float* __restrict__ gb,
    uint32_t* __restrict__ route, uint32_t* __restrict__ cnt,
    float* __restrict__ prob)
{
    const int w = threadIdx.x >> 6;
    const int lane = threadIdx.x & 63;
    const int t = blockIdx.x * 4 + w;
    float acc[NEXP];
#pragma unroll
    for (int e = 0; e < NEXP; ++e) acc[e] = 0.f;
    const float* xr = x + (size_t)t * DM;
#pragma unroll
    for (int j = 0; j < DM / 64; ++j) {
        const int d = j * 64 + lane;
        const float xv = xr[d];
        const float* g = gw + (size_t)d * NEXP;
#pragma unroll
        for (int e = 0; e < NEXP; ++e) acc[e] += xv * g[e];
    }
#pragma unroll
    for (int e = 0; e < NEXP; ++e) {
#pragma unroll
        for (int off = 32; off > 0; off >>= 1)
            acc[e] += __shfl_xor(acc[e], off);
        acc[e] += gb[e];
    }
    if (lane == 0) {
        int e0 = 0; float v0 = acc[0];
#pragma unroll
        for (int e = 1; e < NEXP; ++e) if (acc[e] > v0) { v0 = acc[e]; e0 = e; }
        int e1 = -1; float v1 = -1e30f;
#pragma unroll
        for (int e = 0; e < NEXP; ++e) if (e != e0 && acc[e] > v1) { v1 = acc[e]; e1 = e; }
        const float ex = expf(v1 - v0);
        const float inv = 1.f / (1.f + ex);
        prob[t * 2 + 0] = inv;
        prob[t * 2 + 1] = ex * inv;
        uint32_t pos = atomicAdd(&cnt[e0], 1u);
        route[e0 * T_TOKENS + pos] = (uint32_t)(t * 2);
        pos = atomicAdd(&cnt[e1], 1u);
        route[e1 * T_TOKENS + pos] = (uint32_t)(t * 2 + 1);
    }
}

// ---------------- x fp32 -> bf16 ----------------
__global__ __launch_bounds__(256) void convert_x(const float* __restrict__ x,
                                                 ushort* __restrict__ xb)
{
    const int i = (blockIdx.x * 256 + threadIdx.x) * 4;
    const float4 v = *reinterpret_cast<const float4*>(x + i);
    ushort4 o;
    o.x = f2bf(v.x); o.y = f2bf(v.y); o.z = f2bf(v.z); o.w = f2bf(v.w);
    *reinterpret_cast<ushort4*>(xb + i) = o;
}

// ---------------- grouped expert GEMM ----------------
// A: bf16 rows gathered via route (FIRST: xb by token, else: h by slot), stride KD
// W: fp32 [E][KD][ND], converted to bf16 during LDS staging (transposed)
// FIRST: hout[s][n] = bf16(relu(acc + b1));  else: yout[s][n] = (acc + b2) * prob[s]
template<int KD, int ND, bool FIRST>
__global__ __launch_bounds__(256) void moe_gemm(
    const ushort* __restrict__ Abuf,
    const float* __restrict__ W,
    const float* __restrict__ bias,
    const uint32_t* __restrict__ route,
    const uint32_t* __restrict__ cnt,
    const float* __restrict__ prob,
    ushort* __restrict__ hout,
    float* __restrict__ yout)
{
    const int e = blockIdx.x >> 4;
    const int mt = blockIdx.x & 15;
    const uint32_t cntE = cnt[e];
    const int m0 = mt * 128;
    if ((uint32_t)m0 >= cntE) return;
    const int n0 = blockIdx.y * 128;
    const int tid = threadIdx.x;

    __shared__ ushort Asm[128][40];      // [row][k], +8 pad
    __shared__ ushort Bsm[128][40];      // [col][k] (transposed), +8 pad
    __shared__ uint32_t s_route[128];

    if (tid < 128) {
        const uint32_t idx = (uint32_t)(m0 + tid);
        s_route[tid] = (idx < cntE) ? route[e * T_TOKENS + idx] : 0xFFFFFFFFu;
    }
    __syncthreads();

    // A staging map: 2 threads per row, 16 bf16 (32B) each
    const int ar = tid >> 1;
    const int ah = tid & 1;
    const uint32_t s_a = s_route[ar];
    size_t arow = 0;
    if (s_a != 0xFFFFFFFFu) arow = FIRST ? (size_t)(s_a >> 1) : (size_t)s_a;
    const ushort* asrc = Abuf + arow * KD + ah * 16;

    // B staging map: thread covers 4 cols x 4 k-rows
    const int c4 = tid & 31;   // col quad index
    const int kq = tid >> 5;   // k quad index 0..7
    const float* wbase = W + (size_t)e * KD * ND + (size_t)n0 + (size_t)c4 * 4;

    f32x4 acc[4][4];
#pragma unroll
    for (int i = 0; i < 4; ++i)
#pragma unroll
        for (int j = 0; j < 4; ++j) acc[i][j] = (f32x4){0.f, 0.f, 0.f, 0.f};

    const int lane = tid & 63;
    const int wv = tid >> 6;
    const int wm = wv >> 1, wn = wv & 1;
    const int q = lane & 15, g = lane >> 4;

    for (int k0 = 0; k0 < KD; k0 += 32) {
        {   // stage A 128x32
            const uint4* src = reinterpret_cast<const uint4*>(asrc + k0);
            const uint4 v0 = src[0];
            const uint4 v1 = src[1];
            *reinterpret_cast<uint4*>(&Asm[ar][ah * 16]) = v0;
            *reinterpret_cast<uint4*>(&Asm[ar][ah * 16 + 8]) = v1;
        }
        {   // stage B 32x128 -> transposed bf16
            ushort vals[4][4];
#pragma unroll
            for (int r = 0; r < 4; ++r) {
                const float4 v = *reinterpret_cast<const float4*>(
                    wbase + (size_t)(k0 + kq * 4 + r) * ND);
                vals[r][0] = f2bf(v.x); vals[r][1] = f2bf(v.y);
                vals[r][2] = f2bf(v.z); vals[r][3] = f2bf(v.w);
            }
#pragma unroll
            for (int c = 0; c < 4; ++c) {
                const ushort4 o = { vals[0][c], vals[1][c], vals[2][c], vals[3][c] };
                *reinterpret_cast<ushort4*>(&Bsm[c4 * 4 + c][kq * 4]) = o;
            }
        }
        __syncthreads();
        bf16x8 af[4], bfr[4];
#pragma unroll
        for (int mi = 0; mi < 4; ++mi)
            af[mi] = *reinterpret_cast<const bf16x8*>(&Asm[wm * 64 + mi * 16 + q][g * 8]);
#pragma unroll
        for (int ni = 0; ni < 4; ++ni)
            bfr[ni] = *reinterpret_cast<const bf16x8*>(&Bsm[wn * 64 + ni * 16 + q][g * 8]);
#pragma unroll
        for (int mi = 0; mi < 4; ++mi)
#pragma unroll
            for (int ni = 0; ni < 4; ++ni)
                acc[mi][ni] = __builtin_amdgcn_mfma_f32_16x16x32_bf16(
                    af[mi], bfr[ni], acc[mi][ni], 0, 0, 0);
        __syncthreads();
    }

    // epilogue
#pragma unroll
    for (int mi = 0; mi < 4; ++mi) {
#pragma unroll
        for (int ni = 0; ni < 4; ++ni) {
            const int cl = wn * 64 + ni * 16 + q;
            const int gcol = n0 + cl;
#pragma unroll
            for (int j = 0; j < 4; ++j) {
                const int row = wm * 64 + mi * 16 + g * 4 + j;
                if ((uint32_t)(m0 + row) < cntE) {
                    const uint32_t s = s_route[row];
                    float v = acc[mi][ni][j] + bias[e * ND + gcol];
                    if (FIRST) {
                        v = fmaxf(v, 0.f);
                        hout[(size_t)s * ND + gcol] = f2bf(v);
                    } else {
                        yout[(size_t)s * ND + gcol] = v * prob[s];
                    }
                }
            }
        }
    }
}

// ---------------- combine: out[t] = yc[2t] + yc[2t+1] ----------------
__global__ __launch_bounds__(256) void combine(const float* __restrict__ yc,
                                               float* __restrict__ out)
{
    const int gid = blockIdx.x * 256 + threadIdx.x;   // over T*DM/4
    const int t = gid >> 8;                           // DM/4 = 256 float4 per token
    const int dq = gid & 255;
    const float4 va = reinterpret_cast<const float4*>(yc)[(size_t)(2 * t) * 256 + dq];
    const float4 vb = reinterpret_cast<const float4*>(yc)[(size_t)(2 * t + 1) * 256 + dq];
    const float4 o = { va.x + vb.x, va.y + vb.y, va.z + vb.z, va.w + vb.w };
    reinterpret_cast<float4*>(out)[gid] = o;
}

// ---------------- launch ----------------
extern "C" void kernel_launch(void* const* d_in, const int* in_sizes, int n_in,
                              void* d_out, int out_size, void* d_ws, size_t ws_size,
                              hipStream_t stream)
{
    const float* x  = (const float*)d_in[0];
    const float* gw = (const float*)d_in[1];
    const float* gb = (const float*)d_in[2];
    const float* W1 = (const float*)d_in[3];
    const float* b1 = (const float*)d_in[4];
    const float* W2 = (const float*)d_in[5];
    const float* b2 = (const float*)d_in[6];
    float* out = (float*)d_out;

    char* ws = (char*)d_ws;
    // workspace layout (bytes)
    const size_t OFF_XB    = 0;                      // 2048*1024*2   = 4 MiB
    const size_t OFF_H     = OFF_XB + 4194304;       // 4096*4096*2   = 32 MiB
    const size_t OFF_YC    = OFF_H + 33554432;       // 4096*1024*4   = 16 MiB
    const size_t OFF_ROUTE = OFF_YC + 16777216;      // 8*2048*4      = 64 KiB
    const size_t OFF_CNT   = OFF_ROUTE + 65536;      // 8*4
    const size_t OFF_PROB  = OFF_CNT + 64;           // 4096*4

    ushort*   xb    = (ushort*)(ws + OFF_XB);
    ushort*   h     = (ushort*)(ws + OFF_H);
    float*    yc    = (float*)(ws + OFF_YC);
    uint32_t* route = (uint32_t*)(ws + OFF_ROUTE);
    uint32_t* cnt   = (uint32_t*)(ws + OFF_CNT);
    float*    prob  = (float*)(ws + OFF_PROB);

    hipLaunchKernelGGL(init_cnt, dim3(1), dim3(64), 0, stream, cnt);
    hipLaunchKernelGGL(gate_route, dim3(T_TOKENS / 4), dim3(256), 0, stream,
                       x, gw, gb, route, cnt, prob);
    hipLaunchKernelGGL(convert_x, dim3(T_TOKENS * DM / 1024), dim3(256), 0, stream, x, xb);
    hipLaunchKernelGGL((moe_gemm<DM, DF, true>), dim3(NEXP * 16, DF / 128), dim3(256), 0,
                       stream, xb, W1, b1, route, cnt, prob, h, (float*)nullptr);
    hipLaunchKernelGGL((moe_gemm<DF, DM, false>), dim3(NEXP * 16, DM / 128), dim3(256), 0,
                       stream, h, W2, b2, route, cnt, prob, (ushort*)nullptr, yc);
    hipLaunchKernelGGL(combine, dim3(T_TOKENS * DM / 1024), dim3(256), 0, stream, yc, out);
}

// Round 2
// 625.083 us; speedup vs baseline: 1.2941x; 1.2941x over previous
//
#include <hip/hip_runtime.h>
#include <stdint.h>

#define T_TOKENS 2048
#define DM 1024
#define DF 4096
#define NEXP 8
#define NSLOTS (T_TOKENS * 2)

typedef __bf16 bf16x8 __attribute__((ext_vector_type(8)));
typedef float f32x4 __attribute__((ext_vector_type(4)));

__device__ __forceinline__ ushort f2bf(float f) {
    union { float f; uint32_t u; } v; v.f = f;
    uint32_t r = v.u + 0x7FFFu + ((v.u >> 16) & 1u);
    return (ushort)(r >> 16);
}

__device__ __forceinline__ void gload16(const ushort* g, ushort* l) {
    __builtin_amdgcn_global_load_lds(
        (const __attribute__((address_space(1))) uint32_t*)g,
        (__attribute__((address_space(3))) uint32_t*)l,
        16, 0, 0);
}

// ---------------- init: zero expert counters ----------------
__global__ void init_cnt(uint32_t* cnt) {
    if (threadIdx.x < NEXP) cnt[threadIdx.x] = 0;
}

// ---------------- gating + routing: one wave per token ----------------
__global__ __launch_bounds__(256) void gate_route(
    const float* __restrict__ x, const float* __restrict__ gw,
    const float* __restrict__ gb,
    uint32_t* __restrict__ route, uint32_t* __restrict__ cnt,
    float* __restrict__ prob)
{
    const int w = threadIdx.x >> 6;
    const int lane = threadIdx.x & 63;
    const int t = blockIdx.x * 4 + w;
    float acc[NEXP];
#pragma unroll
    for (int e = 0; e < NEXP; ++e) acc[e] = 0.f;
    const float* xr = x + (size_t)t * DM;
#pragma unroll
    for (int j = 0; j < DM / 64; ++j) {
        const int d = j * 64 + lane;
        const float xv = xr[d];
        const float* g = gw + (size_t)d * NEXP;
#pragma unroll
        for (int e = 0; e < NEXP; ++e) acc[e] += xv * g[e];
    }
#pragma unroll
    for (int e = 0; e < NEXP; ++e) {
#pragma unroll
        for (int off = 32; off > 0; off >>= 1)
            acc[e] += __shfl_xor(acc[e], off);
        acc[e] += gb[e];
    }
    if (lane == 0) {
        int e0 = 0; float v0 = acc[0];
#pragma unroll
        for (int e = 1; e < NEXP; ++e) if (acc[e] > v0) { v0 = acc[e]; e0 = e; }
        int e1 = -1; float v1 = -1e30f;
#pragma unroll
        for (int e = 0; e < NEXP; ++e) if (e != e0 && acc[e] > v1) { v1 = acc[e]; e1 = e; }
        const float ex = expf(v1 - v0);
        const float inv = 1.f / (1.f + ex);
        prob[t * 2 + 0] = inv;
        prob[t * 2 + 1] = ex * inv;
        uint32_t pos = atomicAdd(&cnt[e0], 1u);
        route[e0 * T_TOKENS + pos] = (uint32_t)(t * 2);
        pos = atomicAdd(&cnt[e1], 1u);
        route[e1 * T_TOKENS + pos] = (uint32_t)(t * 2 + 1);
    }
}

// ---------------- x fp32 -> bf16 ----------------
__global__ __launch_bounds__(256) void convert_x(const float* __restrict__ x,
                                                 ushort* __restrict__ xb)
{
    const int i = (blockIdx.x * 256 + threadIdx.x) * 4;
    const float4 v = *reinterpret_cast<const float4*>(x + i);
    ushort4 o;
    o.x = f2bf(v.x); o.y = f2bf(v.y); o.z = f2bf(v.z); o.w = f2bf(v.w);
    *reinterpret_cast<ushort4*>(xb + i) = o;
}

// ---------------- W [E][K][N] f32 -> Wb [E][N][K] bf16 (64x64 tiles) ----------
template<int K, int N>
__global__ __launch_bounds__(256) void conv_transpose(const float* __restrict__ W,
                                                      ushort* __restrict__ Wb)
{
    const int e  = blockIdx.y;
    const int nt = blockIdx.x % (N / 64);
    const int kt = blockIdx.x / (N / 64);
    const int k0 = kt * 64, n0 = nt * 64;
    __shared__ ushort T[64][80];
    const int t = threadIdx.x;
    const int kr = t >> 4, nc = (t & 15) * 4;
    const float* src = W + ((size_t)e * K + k0 + kr) * N + n0 + nc;
#pragma unroll
    for (int i = 0; i < 4; ++i) {
        const float4 v = *reinterpret_cast<const float4*>(src + (size_t)i * 16 * N);
        T[nc + 0][kr + i * 16] = f2bf(v.x);
        T[nc + 1][kr + i * 16] = f2bf(v.y);
        T[nc + 2][kr + i * 16] = f2bf(v.z);
        T[nc + 3][kr + i * 16] = f2bf(v.w);
    }
    __syncthreads();
    const int r = t >> 2, c0 = t & 3;
    ushort* dst = Wb + ((size_t)e * N + n0 + r) * K + k0;
#pragma unroll
    for (int i = 0; i < 2; ++i) {
        const int c = c0 + i * 4;
        const uint4 v = *reinterpret_cast<const uint4*>(&T[r][c * 8]);
        *reinterpret_cast<uint4*>(dst + c * 8) = v;
    }
}

// ---------------- grouped expert GEMM v2 ----------------
// A: bf16 rows gathered via route (stride KD); Wb: bf16 [E][ND][KD] (transposed)
// 128x128 tile, BK=64, global_load_lds staging, st_16x32 swizzle.
template<int KD, int ND, bool FIRST, int SPLIT>
__global__ __launch_bounds__(256) void moe_gemm2(
    const ushort* __restrict__ Abuf,
    const ushort* __restrict__ Wb,
    const float* __restrict__ bias,
    const uint32_t* __restrict__ route,
    const uint32_t* __restrict__ cnt,
    const float* __restrict__ prob,
    ushort* __restrict__ hout,
    float* __restrict__ yout)
{
    const int e  = blockIdx.x >> 4;
    const int mt = blockIdx.x & 15;
    const uint32_t cntE = cnt[e];
    const int m0 = mt * 128;
    if ((uint32_t)m0 >= cntE) return;
    const int n0 = blockIdx.y * 128;
    const int z  = (SPLIT > 1) ? (int)blockIdx.z : 0;
    const int kbeg = z * (KD / SPLIT);
    const int kend = kbeg + (KD / SPLIT);

    __shared__ ushort As[128 * 64];
    __shared__ ushort Bs[128 * 64];
    __shared__ uint32_t s_route[128];

    const int tid = threadIdx.x;
    if (tid < 128) {
        const uint32_t idx = (uint32_t)(m0 + tid);
        s_route[tid] = (idx < cntE) ? route[e * T_TOKENS + idx] : 0xFFFFFFFFu;
    }
    __syncthreads();

    const int w = tid >> 6, l = tid & 63;

    // staging maps: 4 A-chunks + 4 B-chunks (16B each) per thread.
    // LDS dest linear (wave-uniform base + lane*16); global source carries the
    // inverse st_16x32 swizzle (XOR 32B-chunk bit with row bit2).
    const ushort* asrc[4];
    const ushort* bsrc[4];
    ushort* adst[4];
    ushort* bdst[4];
#pragma unroll
    for (int i = 0; i < 4; ++i) {
        const int chunk = (w * 4 + i) * 64 + l;   // 0..1023
        const int row = chunk >> 3;
        const int c   = chunk & 7;
        const int cs  = c ^ (((row >> 2) & 1) << 1);
        const uint32_t s = s_route[row];
        const size_t ar = (s == 0xFFFFFFFFu) ? 0 : (FIRST ? (size_t)(s >> 1) : (size_t)s);
        asrc[i] = Abuf + ar * KD + cs * 8;
        bsrc[i] = Wb + ((size_t)e * ND + n0 + row) * KD + cs * 8;
        adst[i] = As + (w * 4 + i) * 512;
        bdst[i] = Bs + (w * 4 + i) * 512;
    }

    f32x4 acc[4][4];
#pragma unroll
    for (int i = 0; i < 4; ++i)
#pragma unroll
        for (int j = 0; j < 4; ++j) acc[i][j] = (f32x4){0.f, 0.f, 0.f, 0.f};

    const int q = l & 15, g = l >> 4;
    const int wm = w >> 1, wn = w & 1;

    // swizzled fragment byte offsets (compile-time indexed)
    int aoff[4][2], boff[4][2];
#pragma unroll
    for (int mi = 0; mi < 4; ++mi)
#pragma unroll
        for (int ks = 0; ks < 2; ++ks) {
            int row = wm * 64 + mi * 16 + q;
            int b = row * 128 + ks * 64 + g * 16;
            b ^= ((b >> 9) & 1) << 5;
            aoff[mi][ks] = b;
            row = wn * 64 + mi * 16 + q;
            b = row * 128 + ks * 64 + g * 16;
            b ^= ((b >> 9) & 1) << 5;
            boff[mi][ks] = b;
        }

    for (int k0 = kbeg; k0 < kend; k0 += 64) {
#pragma unroll
        for (int i = 0; i < 4; ++i) gload16(asrc[i] + k0, adst[i]);
#pragma unroll
        for (int i = 0; i < 4; ++i) gload16(bsrc[i] + k0, bdst[i]);
        __syncthreads();
#pragma unroll
        for (int ks = 0; ks < 2; ++ks) {
            bf16x8 af[4], bv[4];
#pragma unroll
            for (int mi = 0; mi < 4; ++mi)
                af[mi] = *reinterpret_cast<const bf16x8*>((const char*)As + aoff[mi][ks]);
#pragma unroll
            for (int ni = 0; ni < 4; ++ni)
                bv[ni] = *reinterpret_cast<const bf16x8*>((const char*)Bs + boff[ni][ks]);
#pragma unroll
            for (int mi = 0; mi < 4; ++mi)
#pragma unroll
                for (int ni = 0; ni < 4; ++ni)
                    acc[mi][ni] = __builtin_amdgcn_mfma_f32_16x16x32_bf16(
                        af[mi], bv[ni], acc[mi][ni], 0, 0, 0);
        }
        __syncthreads();
    }

    // epilogue
    const float* brow = bias + (size_t)e * ND;
#pragma unroll
    for (int mi = 0; mi < 4; ++mi) {
#pragma unroll
        for (int ni = 0; ni < 4; ++ni) {
            const int gcol = n0 + wn * 64 + ni * 16 + q;
            const float bv = (SPLIT == 1 || z == 0) ? brow[gcol] : 0.f;
#pragma unroll
            for (int j = 0; j < 4; ++j) {
                const int row = wm * 64 + mi * 16 + g * 4 + j;
                if ((uint32_t)(m0 + row) < cntE) {
                    const uint32_t s = s_route[row];
                    float v = acc[mi][ni][j] + bv;
                    if (FIRST) {
                        v = fmaxf(v, 0.f);
                        hout[(size_t)s * ND + gcol] = f2bf(v);
                    } else {
                        yout[((size_t)z * NSLOTS + s) * ND + gcol] = v * prob[s];
                    }
                }
            }
        }
    }
}

// ---------------- combine (split-K=2): out[t] = sum of 4 yc rows ----------------
__global__ __launch_bounds__(256) void combine2(const float* __restrict__ yc,
                                                float* __restrict__ out)
{
    const int gid = blockIdx.x * 256 + threadIdx.x;   // over T*DM/4
    const int t = gid >> 8;
    const int dq = gid & 255;
    const float4* Y = reinterpret_cast<const float4*>(yc);
    const float4 a = Y[(size_t)(2 * t) * 256 + dq];
    const float4 b = Y[(size_t)(2 * t + 1) * 256 + dq];
    const float4 c = Y[((size_t)NSLOTS + 2 * t) * 256 + dq];
    const float4 d = Y[((size_t)NSLOTS + 2 * t + 1) * 256 + dq];
    const float4 o = { a.x + b.x + c.x + d.x, a.y + b.y + c.y + d.y,
                       a.z + b.z + c.z + d.z, a.w + b.w + c.w + d.w };
    reinterpret_cast<float4*>(out)[gid] = o;
}

// ================= fallback path (round-1, works in ~55 MB ws) =================
template<int KD, int ND, bool FIRST>
__global__ __launch_bounds__(256) void moe_gemm_v1(
    const ushort* __restrict__ Abuf, const float* __restrict__ W,
    const float* __restrict__ bias, const uint32_t* __restrict__ route,
    const uint32_t* __restrict__ cnt, const float* __restrict__ prob,
    ushort* __restrict__ hout, float* __restrict__ yout)
{
    const int e = blockIdx.x >> 4;
    const int mt = blockIdx.x & 15;
    const uint32_t cntE = cnt[e];
    const int m0 = mt * 128;
    if ((uint32_t)m0 >= cntE) return;
    const int n0 = blockIdx.y * 128;
    const int tid = threadIdx.x;
    __shared__ ushort Asm[128][40];
    __shared__ ushort Bsm[128][40];
    __shared__ uint32_t s_route[128];
    if (tid < 128) {
        const uint32_t idx = (uint32_t)(m0 + tid);
        s_route[tid] = (idx < cntE) ? route[e * T_TOKENS + idx] : 0xFFFFFFFFu;
    }
    __syncthreads();
    const int ar = tid >> 1, ah = tid & 1;
    const uint32_t s_a = s_route[ar];
    size_t arow = 0;
    if (s_a != 0xFFFFFFFFu) arow = FIRST ? (size_t)(s_a >> 1) : (size_t)s_a;
    const ushort* asrc = Abuf + arow * KD + ah * 16;
    const int c4 = tid & 31, kq = tid >> 5;
    const float* wbase = W + (size_t)e * KD * ND + (size_t)n0 + (size_t)c4 * 4;
    f32x4 acc[4][4];
#pragma unroll
    for (int i = 0; i < 4; ++i)
#pragma unroll
        for (int j = 0; j < 4; ++j) acc[i][j] = (f32x4){0.f, 0.f, 0.f, 0.f};
    const int lane = tid & 63, wv = tid >> 6;
    const int wm = wv >> 1, wn = wv & 1;
    const int q = lane & 15, g = lane >> 4;
    for (int k0 = 0; k0 < KD; k0 += 32) {
        {
            const uint4* src = reinterpret_cast<const uint4*>(asrc + k0);
            const uint4 v0 = src[0];
            const uint4 v1 = src[1];
            *reinterpret_cast<uint4*>(&Asm[ar][ah * 16]) = v0;
            *reinterpret_cast<uint4*>(&Asm[ar][ah * 16 + 8]) = v1;
        }
        {
            ushort vals[4][4];
#pragma unroll
            for (int r = 0; r < 4; ++r) {
                const float4 v = *reinterpret_cast<const float4*>(
                    wbase + (size_t)(k0 + kq * 4 + r) * ND);
                vals[r][0] = f2bf(v.x); vals[r][1] = f2bf(v.y);
                vals[r][2] = f2bf(v.z); vals[r][3] = f2bf(v.w);
            }
#pragma unroll
            for (int c = 0; c < 4; ++c) {
                const ushort4 o = { vals[0][c], vals[1][c], vals[2][c], vals[3][c] };
                *reinterpret_cast<ushort4*>(&Bsm[c4 * 4 + c][kq * 4]) = o;
            }
        }
        __syncthreads();
        bf16x8 af[4], bfr[4];
#pragma unroll
        for (int mi = 0; mi < 4; ++mi)
            af[mi] = *reinterpret_cast<const bf16x8*>(&Asm[wm * 64 + mi * 16 + q][g * 8]);
#pragma unroll
        for (int ni = 0; ni < 4; ++ni)
            bfr[ni] = *reinterpret_cast<const bf16x8*>(&Bsm[wn * 64 + ni * 16 + q][g * 8]);
#pragma unroll
        for (int mi = 0; mi < 4; ++mi)
#pragma unroll
            for (int ni = 0; ni < 4; ++ni)
                acc[mi][ni] = __builtin_amdgcn_mfma_f32_16x16x32_bf16(
                    af[mi], bfr[ni], acc[mi][ni], 0, 0, 0);
        __syncthreads();
    }
#pragma unroll
    for (int mi = 0; mi < 4; ++mi) {
#pragma unroll
        for (int ni = 0; ni < 4; ++ni) {
            const int gcol = n0 + wn * 64 + ni * 16 + q;
#pragma unroll
            for (int j = 0; j < 4; ++j) {
                const int row = wm * 64 + mi * 16 + g * 4 + j;
                if ((uint32_t)(m0 + row) < cntE) {
                    const uint32_t s = s_route[row];
                    float v = acc[mi][ni][j] + bias[e * ND + gcol];
                    if (FIRST) {
                        v = fmaxf(v, 0.f);
                        hout[(size_t)s * ND + gcol] = f2bf(v);
                    } else {
                        yout[(size_t)s * ND + gcol] = v * prob[s];
                    }
                }
            }
        }
    }
}

__global__ __launch_bounds__(256) void combine1(const float* __restrict__ yc,
                                                float* __restrict__ out)
{
    const int gid = blockIdx.x * 256 + threadIdx.x;
    const int t = gid >> 8;
    const int dq = gid & 255;
    const float4 va = reinterpret_cast<const float4*>(yc)[(size_t)(2 * t) * 256 + dq];
    const float4 vb = reinterpret_cast<const float4*>(yc)[(size_t)(2 * t + 1) * 256 + dq];
    const float4 o = { va.x + vb.x, va.y + vb.y, va.z + vb.z, va.w + vb.w };
    reinterpret_cast<float4*>(out)[gid] = o;
}

// ---------------- launch ----------------
extern "C" void kernel_launch(void* const* d_in, const int* in_sizes, int n_in,
                              void* d_out, int out_size, void* d_ws, size_t ws_size,
                              hipStream_t stream)
{
    const float* x  = (const float*)d_in[0];
    const float* gw = (const float*)d_in[1];
    const float* gb = (const float*)d_in[2];
    const float* W1 = (const float*)d_in[3];
    const float* b1 = (const float*)d_in[4];
    const float* W2 = (const float*)d_in[5];
    const float* b2 = (const float*)d_in[6];
    float* out = (float*)d_out;
    char* ws = (char*)d_ws;

    // ---- big layout (needs ~206 MB) ----
    const size_t OFF_XB    = 0;                        // 4 MiB
    const size_t OFF_H     = 4194304;                  // 32 MiB
    const size_t OFF_YC    = 37748736;                 // 32 MiB (2 splits)
    const size_t OFF_ROUTE = 71303168;                 // 64 KiB
    const size_t OFF_CNT   = 71368704;
    const size_t OFF_PROB  = 71368768;
    const size_t OFF_W1B   = 71385152;                 // 64 MiB
    const size_t OFF_W2B   = 138494016;                // 64 MiB
    const size_t NEED      = 205602880ull;

    if (ws_size >= NEED) {
        ushort*   xb    = (ushort*)(ws + OFF_XB);
        ushort*   h     = (ushort*)(ws + OFF_H);
        float*    yc    = (float*)(ws + OFF_YC);
        uint32_t* route = (uint32_t*)(ws + OFF_ROUTE);
        uint32_t* cnt   = (uint32_t*)(ws + OFF_CNT);
        float*    prob  = (float*)(ws + OFF_PROB);
        ushort*   w1b   = (ushort*)(ws + OFF_W1B);
        ushort*   w2b   = (ushort*)(ws + OFF_W2B);

        hipLaunchKernelGGL(init_cnt, dim3(1), dim3(64), 0, stream, cnt);
        hipLaunchKernelGGL(gate_route, dim3(T_TOKENS / 4), dim3(256), 0, stream,
                           x, gw, gb, route, cnt, prob);
        hipLaunchKernelGGL(convert_x, dim3(T_TOKENS * DM / 1024), dim3(256), 0, stream, x, xb);
        hipLaunchKernelGGL((conv_transpose<DM, DF>), dim3((DM / 64) * (DF / 64), NEXP),
                           dim3(256), 0, stream, W1, w1b);
        hipLaunchKernelGGL((conv_transpose<DF, DM>), dim3((DF / 64) * (DM / 64), NEXP),
                           dim3(256), 0, stream, W2, w2b);
        hipLaunchKernelGGL((moe_gemm2<DM, DF, true, 1>), dim3(NEXP * 16, DF / 128, 1),
                           dim3(256), 0, stream, xb, w1b, b1, route, cnt, prob,
                           h, (float*)nullptr);
        hipLaunchKernelGGL((moe_gemm2<DF, DM, false, 2>), dim3(NEXP * 16, DM / 128, 2),
                           dim3(256), 0, stream, h, w2b, b2, route, cnt, prob,
                           (ushort*)nullptr, yc);
        hipLaunchKernelGGL(combine2, dim3(T_TOKENS * DM / 1024), dim3(256), 0, stream, yc, out);
    } else {
        // ---- fallback: round-1 layout (~55 MB) ----
        const size_t F_XB = 0, F_H = 4194304, F_YC = 37748736;
        const size_t F_ROUTE = 54525952, F_CNT = 54591488, F_PROB = 54591552;
        ushort*   xb    = (ushort*)(ws + F_XB);
        ushort*   h     = (ushort*)(ws + F_H);
        float*    yc    = (float*)(ws + F_YC);
        uint32_t* route = (uint32_t*)(ws + F_ROUTE);
        uint32_t* cnt   = (uint32_t*)(ws + F_CNT);
        float*    prob  = (float*)(ws + F_PROB);

        hipLaunchKernelGGL(init_cnt, dim3(1), dim3(64), 0, stream, cnt);
        hipLaunchKernelGGL(gate_route, dim3(T_TOKENS / 4), dim3(256), 0, stream,
                           x, gw, gb, route, cnt, prob);
        hipLaunchKernelGGL(convert_x, dim3(T_TOKENS * DM / 1024), dim3(256), 0, stream, x, xb);
        hipLaunchKernelGGL((moe_gemm_v1<DM, DF, true>), dim3(NEXP * 16, DF / 128),
                           dim3(256), 0, stream, xb, W1, b1, route, cnt, prob,
                           h, (float*)nullptr);
        hipLaunchKernelGGL((moe_gemm_v1<DF, DM, false>), dim3(NEXP * 16, DM / 128),
                           dim3(256), 0, stream, h, W2, b2, route, cnt, prob,
                           (ushort*)nullptr, yc);
        hipLaunchKernelGGL(combine1, dim3(T_TOKENS * DM / 1024), dim3(256), 0, stream, yc, out);
    }
}

// Round 3
// 335.872 us; speedup vs baseline: 2.4085x; 1.8611x over previous
//
#include <hip/hip_runtime.h>
#include <stdint.h>

#define T_TOKENS 2048
#define DM 1024
#define DF 4096
#define NEXP 8
#define NSLOTS (T_TOKENS * 2)

typedef __bf16 bf16x8 __attribute__((ext_vector_type(8)));
typedef float f32x4 __attribute__((ext_vector_type(4)));

__device__ __forceinline__ ushort f2bf(float f) {
    union { float f; uint32_t u; } v; v.f = f;
    uint32_t r = v.u + 0x7FFFu + ((v.u >> 16) & 1u);
    return (ushort)(r >> 16);
}

__device__ __forceinline__ void gload16(const ushort* g, ushort* l) {
    __builtin_amdgcn_global_load_lds(
        (const __attribute__((address_space(1))) uint32_t*)g,
        (__attribute__((address_space(3))) uint32_t*)l,
        16, 0, 0);
}

// ---------------- init: zero expert counters ----------------
__global__ void init_cnt(uint32_t* cnt) {
    if (threadIdx.x < NEXP) cnt[threadIdx.x] = 0;
}

// ---------------- gating + routing: one wave per token ----------------
__global__ __launch_bounds__(256) void gate_route(
    const float* __restrict__ x, const float* __restrict__ gw,
    const float* __restrict__ gb,
    uint32_t* __restrict__ route, uint32_t* __restrict__ cnt,
    float* __restrict__ prob)
{
    const int w = threadIdx.x >> 6;
    const int lane = threadIdx.x & 63;
    const int t = blockIdx.x * 4 + w;
    float acc[NEXP];
#pragma unroll
    for (int e = 0; e < NEXP; ++e) acc[e] = 0.f;
    const float* xr = x + (size_t)t * DM;
#pragma unroll
    for (int j = 0; j < DM / 64; ++j) {
        const int d = j * 64 + lane;
        const float xv = xr[d];
        const float* g = gw + (size_t)d * NEXP;
#pragma unroll
        for (int e = 0; e < NEXP; ++e) acc[e] += xv * g[e];
    }
#pragma unroll
    for (int e = 0; e < NEXP; ++e) {
#pragma unroll
        for (int off = 32; off > 0; off >>= 1)
            acc[e] += __shfl_xor(acc[e], off);
        acc[e] += gb[e];
    }
    if (lane == 0) {
        int e0 = 0; float v0 = acc[0];
#pragma unroll
        for (int e = 1; e < NEXP; ++e) if (acc[e] > v0) { v0 = acc[e]; e0 = e; }
        int e1 = -1; float v1 = -1e30f;
#pragma unroll
        for (int e = 0; e < NEXP; ++e) if (e != e0 && acc[e] > v1) { v1 = acc[e]; e1 = e; }
        const float ex = expf(v1 - v0);
        const float inv = 1.f / (1.f + ex);
        prob[t * 2 + 0] = inv;
        prob[t * 2 + 1] = ex * inv;
        uint32_t pos = atomicAdd(&cnt[e0], 1u);
        route[e0 * T_TOKENS + pos] = (uint32_t)(t * 2);
        pos = atomicAdd(&cnt[e1], 1u);
        route[e1 * T_TOKENS + pos] = (uint32_t)(t * 2 + 1);
    }
}

// ---------------- x fp32 -> bf16 ----------------
__global__ __launch_bounds__(256) void convert_x(const float* __restrict__ x,
                                                 ushort* __restrict__ xb)
{
    const int i = (blockIdx.x * 256 + threadIdx.x) * 4;
    const float4 v = *reinterpret_cast<const float4*>(x + i);
    ushort4 o;
    o.x = f2bf(v.x); o.y = f2bf(v.y); o.z = f2bf(v.z); o.w = f2bf(v.w);
    *reinterpret_cast<ushort4*>(xb + i) = o;
}

// ---------------- W [E][K][N] f32 -> Wb [E][N][K] bf16 (64x64 tiles) ----------
template<int K, int N>
__global__ __launch_bounds__(256) void conv_transpose(const float* __restrict__ W,
                                                      ushort* __restrict__ Wb)
{
    const int e  = blockIdx.y;
    const int nt = blockIdx.x % (N / 64);
    const int kt = blockIdx.x / (N / 64);
    const int k0 = kt * 64, n0 = nt * 64;
    __shared__ ushort T[64][80];
    const int t = threadIdx.x;
    const int kr = t >> 4, nc = (t & 15) * 4;
    const float* src = W + ((size_t)e * K + k0 + kr) * N + n0 + nc;
#pragma unroll
    for (int i = 0; i < 4; ++i) {
        const float4 v = *reinterpret_cast<const float4*>(src + (size_t)i * 16 * N);
        T[nc + 0][kr + i * 16] = f2bf(v.x);
        T[nc + 1][kr + i * 16] = f2bf(v.y);
        T[nc + 2][kr + i * 16] = f2bf(v.z);
        T[nc + 3][kr + i * 16] = f2bf(v.w);
    }
    __syncthreads();
    const int r = t >> 2, c0 = t & 3;
    ushort* dst = Wb + ((size_t)e * N + n0 + r) * K + k0;
#pragma unroll
    for (int i = 0; i < 2; ++i) {
        const int c = c0 + i * 4;
        const uint4 v = *reinterpret_cast<const uint4*>(&T[r][c * 8]);
        *reinterpret_cast<uint4*>(dst + c * 8) = v;
    }
}

// ---------------- grouped expert GEMM v3: 2-phase pipelined ----------------
// A: bf16 rows gathered via route (stride KD); Wb: bf16 [E][ND][KD] (transposed)
// 128x128 tile, BK=64, double-buffered global_load_lds staging, st_16x32
// swizzle (inverse on source, forward on ds_read). 1D grid, n-tile fastest
// (NT % 8 == 0 so same-(e,nt) m-tiles share an XCD's L2 for the B panel).
template<int KD, int ND, bool FIRST, int SPLIT, int NT>
__global__ __launch_bounds__(256, 2) void moe_gemm3(
    const ushort* __restrict__ Abuf,
    const ushort* __restrict__ Wb,
    const float* __restrict__ bias,
    const uint32_t* __restrict__ route,
    const uint32_t* __restrict__ cnt,
    const float* __restrict__ prob,
    ushort* __restrict__ hout,
    float* __restrict__ yout)
{
    const int bx = blockIdx.x;
    const int e  = bx / (16 * NT);
    const int mt = (bx / NT) & 15;
    const int nt = bx % NT;
    const uint32_t cntE = cnt[e];
    const int m0 = mt * 128;
    if ((uint32_t)m0 >= cntE) return;
    const int n0 = nt * 128;
    const int z  = (SPLIT > 1) ? (int)blockIdx.z : 0;
    const int kbeg = z * (KD / SPLIT);
    const int niter = (KD / SPLIT) / 64;

    __shared__ ushort As[2][128 * 64];
    __shared__ ushort Bs[2][128 * 64];
    __shared__ uint32_t s_route[128];

    const int tid = threadIdx.x;
    if (tid < 128) {
        const uint32_t idx = (uint32_t)(m0 + tid);
        s_route[tid] = (idx < cntE) ? route[e * T_TOKENS + idx] : 0xFFFFFFFFu;
    }
    __syncthreads();

    const int w = tid >> 6, l = tid & 63;

    // staging maps: 4 A-chunks + 4 B-chunks (16B each) per thread.
    // LDS dest linear (wave-uniform base + lane*16); global source carries the
    // inverse st_16x32 swizzle (XOR 32B-chunk bit with row bit2).
    const ushort* asrc[4];
    const ushort* bsrc[4];
#pragma unroll
    for (int i = 0; i < 4; ++i) {
        const int chunk = (w * 4 + i) * 64 + l;   // 0..1023
        const int row = chunk >> 3;
        const int c   = chunk & 7;
        const int cs  = c ^ (((row >> 2) & 1) << 1);
        const uint32_t s = s_route[row];
        const size_t ar = (s == 0xFFFFFFFFu) ? 0 : (FIRST ? (size_t)(s >> 1) : (size_t)s);
        asrc[i] = Abuf + ar * KD + cs * 8 + kbeg;
        bsrc[i] = Wb + ((size_t)e * ND + n0 + row) * KD + cs * 8 + kbeg;
    }

    f32x4 acc[4][4];
#pragma unroll
    for (int i = 0; i < 4; ++i)
#pragma unroll
        for (int j = 0; j < 4; ++j) acc[i][j] = (f32x4){0.f, 0.f, 0.f, 0.f};

    const int q = l & 15, g = l >> 4;
    const int wm = w >> 1, wn = w & 1;

    // swizzled fragment byte offsets (compile-time indexed)
    int aoff[4][2], boff[4][2];
#pragma unroll
    for (int mi = 0; mi < 4; ++mi)
#pragma unroll
        for (int ks = 0; ks < 2; ++ks) {
            int row = wm * 64 + mi * 16 + q;
            int b = row * 128 + ks * 64 + g * 16;
            b ^= ((b >> 9) & 1) << 5;
            aoff[mi][ks] = b;
            row = wn * 64 + mi * 16 + q;
            b = row * 128 + ks * 64 + g * 16;
            b ^= ((b >> 9) & 1) << 5;
            boff[mi][ks] = b;
        }

    // ---- 2-phase pipeline (T3-minimum): STAGE(t+1) before compute(t),
    //      one drain+barrier per K-step.
    ushort* const abase0 = &As[0][0];
    ushort* const bbase0 = &Bs[0][0];

    // prologue: stage tile 0 into buf 0
#pragma unroll
    for (int i = 0; i < 4; ++i) gload16(asrc[i], abase0 + (w * 4 + i) * 512);
#pragma unroll
    for (int i = 0; i < 4; ++i) gload16(bsrc[i], bbase0 + (w * 4 + i) * 512);
    __syncthreads();

    int cur = 0;
    for (int t = 0; t < niter; ++t) {
        // issue next-tile prefetch into the other buffer
        if (t + 1 < niter) {
            ushort* ad = abase0 + (cur ^ 1) * (128 * 64) + (w * 4) * 512;
            ushort* bd = bbase0 + (cur ^ 1) * (128 * 64) + (w * 4) * 512;
            const int k1 = (t + 1) * 64;
#pragma unroll
            for (int i = 0; i < 4; ++i) gload16(asrc[i] + k1, ad + i * 512);
#pragma unroll
            for (int i = 0; i < 4; ++i) gload16(bsrc[i] + k1, bd + i * 512);
        }
        // compute current tile
        const char* Ab = (const char*)(abase0 + cur * (128 * 64));
        const char* Bb = (const char*)(bbase0 + cur * (128 * 64));
#pragma unroll
        for (int ks = 0; ks < 2; ++ks) {
            bf16x8 af[4], bv[4];
#pragma unroll
            for (int mi = 0; mi < 4; ++mi)
                af[mi] = *reinterpret_cast<const bf16x8*>(Ab + aoff[mi][ks]);
#pragma unroll
            for (int ni = 0; ni < 4; ++ni)
                bv[ni] = *reinterpret_cast<const bf16x8*>(Bb + boff[ni][ks]);
            __builtin_amdgcn_s_setprio(1);
#pragma unroll
            for (int mi = 0; mi < 4; ++mi)
#pragma unroll
                for (int ni = 0; ni < 4; ++ni)
                    acc[mi][ni] = __builtin_amdgcn_mfma_f32_16x16x32_bf16(
                        af[mi], bv[ni], acc[mi][ni], 0, 0, 0);
            __builtin_amdgcn_s_setprio(0);
        }
        __syncthreads();   // compiler emits vmcnt(0) lgkmcnt(0) drain here
        cur ^= 1;
    }

    // epilogue
    const float* brow = bias + (size_t)e * ND;
#pragma unroll
    for (int mi = 0; mi < 4; ++mi) {
#pragma unroll
        for (int ni = 0; ni < 4; ++ni) {
            const int gcol = n0 + wn * 64 + ni * 16 + q;
            const float bv = (SPLIT == 1 || z == 0) ? brow[gcol] : 0.f;
#pragma unroll
            for (int j = 0; j < 4; ++j) {
                const int row = wm * 64 + mi * 16 + g * 4 + j;
                if ((uint32_t)(m0 + row) < cntE) {
                    const uint32_t s = s_route[row];
                    float v = acc[mi][ni][j] + bv;
                    if (FIRST) {
                        v = fmaxf(v, 0.f);
                        hout[(size_t)s * ND + gcol] = f2bf(v);
                    } else {
                        yout[((size_t)z * NSLOTS + s) * ND + gcol] = v * prob[s];
                    }
                }
            }
        }
    }
}

// ---------------- combine (split-K=2): out[t] = sum of 4 yc rows ----------------
__global__ __launch_bounds__(256) void combine2(const float* __restrict__ yc,
                                                float* __restrict__ out)
{
    const int gid = blockIdx.x * 256 + threadIdx.x;   // over T*DM/4
    const int t = gid >> 8;
    const int dq = gid & 255;
    const float4* Y = reinterpret_cast<const float4*>(yc);
    const float4 a = Y[(size_t)(2 * t) * 256 + dq];
    const float4 b = Y[(size_t)(2 * t + 1) * 256 + dq];
    const float4 c = Y[((size_t)NSLOTS + 2 * t) * 256 + dq];
    const float4 d = Y[((size_t)NSLOTS + 2 * t + 1) * 256 + dq];
    const float4 o = { a.x + b.x + c.x + d.x, a.y + b.y + c.y + d.y,
                       a.z + b.z + c.z + d.z, a.w + b.w + c.w + d.w };
    reinterpret_cast<float4*>(out)[gid] = o;
}

// ================= fallback path (round-1, works in ~55 MB ws) =================
template<int KD, int ND, bool FIRST>
__global__ __launch_bounds__(256) void moe_gemm_v1(
    const ushort* __restrict__ Abuf, const float* __restrict__ W,
    const float* __restrict__ bias, const uint32_t* __restrict__ route,
    const uint32_t* __restrict__ cnt, const float* __restrict__ prob,
    ushort* __restrict__ hout, float* __restrict__ yout)
{
    const int e = blockIdx.x >> 4;
    const int mt = blockIdx.x & 15;
    const uint32_t cntE = cnt[e];
    const int m0 = mt * 128;
    if ((uint32_t)m0 >= cntE) return;
    const int n0 = blockIdx.y * 128;
    const int tid = threadIdx.x;
    __shared__ ushort Asm[128][40];
    __shared__ ushort Bsm[128][40];
    __shared__ uint32_t s_route[128];
    if (tid < 128) {
        const uint32_t idx = (uint32_t)(m0 + tid);
        s_route[tid] = (idx < cntE) ? route[e * T_TOKENS + idx] : 0xFFFFFFFFu;
    }
    __syncthreads();
    const int ar = tid >> 1, ah = tid & 1;
    const uint32_t s_a = s_route[ar];
    size_t arow = 0;
    if (s_a != 0xFFFFFFFFu) arow = FIRST ? (size_t)(s_a >> 1) : (size_t)s_a;
    const ushort* asrc = Abuf + arow * KD + ah * 16;
    const int c4 = tid & 31, kq = tid >> 5;
    const float* wbase = W + (size_t)e * KD * ND + (size_t)n0 + (size_t)c4 * 4;
    f32x4 acc[4][4];
#pragma unroll
    for (int i = 0; i < 4; ++i)
#pragma unroll
        for (int j = 0; j < 4; ++j) acc[i][j] = (f32x4){0.f, 0.f, 0.f, 0.f};
    const int lane = tid & 63, wv = tid >> 6;
    const int wm = wv >> 1, wn = wv & 1;
    const int q = lane & 15, g = lane >> 4;
    for (int k0 = 0; k0 < KD; k0 += 32) {
        {
            const uint4* src = reinterpret_cast<const uint4*>(asrc + k0);
            const uint4 v0 = src[0];
            const uint4 v1 = src[1];
            *reinterpret_cast<uint4*>(&Asm[ar][ah * 16]) = v0;
            *reinterpret_cast<uint4*>(&Asm[ar][ah * 16 + 8]) = v1;
        }
        {
            ushort vals[4][4];
#pragma unroll
            for (int r = 0; r < 4; ++r) {
                const float4 v = *reinterpret_cast<const float4*>(
                    wbase + (size_t)(k0 + kq * 4 + r) * ND);
                vals[r][0] = f2bf(v.x); vals[r][1] = f2bf(v.y);
                vals[r][2] = f2bf(v.z); vals[r][3] = f2bf(v.w);
            }
#pragma unroll
            for (int c = 0; c < 4; ++c) {
                const ushort4 o = { vals[0][c], vals[1][c], vals[2][c], vals[3][c] };
                *reinterpret_cast<ushort4*>(&Bsm[c4 * 4 + c][kq * 4]) = o;
            }
        }
        __syncthreads();
        bf16x8 af[4], bfr[4];
#pragma unroll
        for (int mi = 0; mi < 4; ++mi)
            af[mi] = *reinterpret_cast<const bf16x8*>(&Asm[wm * 64 + mi * 16 + q][g * 8]);
#pragma unroll
        for (int ni = 0; ni < 4; ++ni)
            bfr[ni] = *reinterpret_cast<const bf16x8*>(&Bsm[wn * 64 + ni * 16 + q][g * 8]);
#pragma unroll
        for (int mi = 0; mi < 4; ++mi)
#pragma unroll
            for (int ni = 0; ni < 4; ++ni)
                acc[mi][ni] = __builtin_amdgcn_mfma_f32_16x16x32_bf16(
                    af[mi], bfr[ni], acc[mi][ni], 0, 0, 0);
        __syncthreads();
    }
#pragma unroll
    for (int mi = 0; mi < 4; ++mi) {
#pragma unroll
        for (int ni = 0; ni < 4; ++ni) {
            const int gcol = n0 + wn * 64 + ni * 16 + q;
#pragma unroll
            for (int j = 0; j < 4; ++j) {
                const int row = wm * 64 + mi * 16 + g * 4 + j;
                if ((uint32_t)(m0 + row) < cntE) {
                    const uint32_t s = s_route[row];
                    float v = acc[mi][ni][j] + bias[e * ND + gcol];
                    if (FIRST) {
                        v = fmaxf(v, 0.f);
                        hout[(size_t)s * ND + gcol] = f2bf(v);
                    } else {
                        yout[(size_t)s * ND + gcol] = v * prob[s];
                    }
                }
            }
        }
    }
}

__global__ __launch_bounds__(256) void combine1(const float* __restrict__ yc,
                                                float* __restrict__ out)
{
    const int gid = blockIdx.x * 256 + threadIdx.x;
    const int t = gid >> 8;
    const int dq = gid & 255;
    const float4 va = reinterpret_cast<const float4*>(yc)[(size_t)(2 * t) * 256 + dq];
    const float4 vb = reinterpret_cast<const float4*>(yc)[(size_t)(2 * t + 1) * 256 + dq];
    const float4 o = { va.x + vb.x, va.y + vb.y, va.z + vb.z, va.w + vb.w };
    reinterpret_cast<float4*>(out)[gid] = o;
}

// ---------------- launch ----------------
extern "C" void kernel_launch(void* const* d_in, const int* in_sizes, int n_in,
                              void* d_out, int out_size, void* d_ws, size_t ws_size,
                              hipStream_t stream)
{
    const float* x  = (const float*)d_in[0];
    const float* gw = (const float*)d_in[1];
    const float* gb = (const float*)d_in[2];
    const float* W1 = (const float*)d_in[3];
    const float* b1 = (const float*)d_in[4];
    const float* W2 = (const float*)d_in[5];
    const float* b2 = (const float*)d_in[6];
    float* out = (float*)d_out;
    char* ws = (char*)d_ws;

    // ---- big layout (needs ~206 MB) ----
    const size_t OFF_XB    = 0;                        // 4 MiB
    const size_t OFF_H     = 4194304;                  // 32 MiB
    const size_t OFF_YC    = 37748736;                 // 32 MiB (2 splits)
    const size_t OFF_ROUTE = 71303168;                 // 64 KiB
    const size_t OFF_CNT   = 71368704;
    const size_t OFF_PROB  = 71368768;
    const size_t OFF_W1B   = 71385152;                 // 64 MiB
    const size_t OFF_W2B   = 138494016;                // 64 MiB
    const size_t NEED      = 205602880ull;

    if (ws_size >= NEED) {
        ushort*   xb    = (ushort*)(ws + OFF_XB);
        ushort*   h     = (ushort*)(ws + OFF_H);
        float*    yc    = (float*)(ws + OFF_YC);
        uint32_t* route = (uint32_t*)(ws + OFF_ROUTE);
        uint32_t* cnt   = (uint32_t*)(ws + OFF_CNT);
        float*    prob  = (float*)(ws + OFF_PROB);
        ushort*   w1b   = (ushort*)(ws + OFF_W1B);
        ushort*   w2b   = (ushort*)(ws + OFF_W2B);

        hipLaunchKernelGGL(init_cnt, dim3(1), dim3(64), 0, stream, cnt);
        hipLaunchKernelGGL(gate_route, dim3(T_TOKENS / 4), dim3(256), 0, stream,
                           x, gw, gb, route, cnt, prob);
        hipLaunchKernelGGL(convert_x, dim3(T_TOKENS * DM / 1024), dim3(256), 0, stream, x, xb);
        hipLaunchKernelGGL((conv_transpose<DM, DF>), dim3((DM / 64) * (DF / 64), NEXP),
                           dim3(256), 0, stream, W1, w1b);
        hipLaunchKernelGGL((conv_transpose<DF, DM>), dim3((DF / 64) * (DM / 64), NEXP),
                           dim3(256), 0, stream, W2, w2b);
        // GEMM1: 1D grid, n-tile fastest (NT=32)
        hipLaunchKernelGGL((moe_gemm3<DM, DF, true, 1, 32>),
                           dim3(NEXP * 16 * 32, 1, 1), dim3(256), 0, stream,
                           xb, w1b, b1, route, cnt, prob, h, (float*)nullptr);
        // GEMM2: split-K=2 in grid z (NT=8)
        hipLaunchKernelGGL((moe_gemm3<DF, DM, false, 2, 8>),
                           dim3(NEXP * 16 * 8, 1, 2), dim3(256), 0, stream,
                           h, w2b, b2, route, cnt, prob, (ushort*)nullptr, yc);
        hipLaunchKernelGGL(combine2, dim3(T_TOKENS * DM / 1024), dim3(256), 0, stream, yc, out);
    } else {
        // ---- fallback: round-1 layout (~55 MB) ----
        const size_t F_XB = 0, F_H = 4194304, F_YC = 37748736;
        const size_t F_ROUTE = 54525952, F_CNT = 54591488, F_PROB = 54591552;
        ushort*   xb    = (ushort*)(ws + F_XB);
        ushort*   h     = (ushort*)(ws + F_H);
        float*    yc    = (float*)(ws + F_YC);
        uint32_t* route = (uint32_t*)(ws + F_ROUTE);
        uint32_t* cnt   = (uint32_t*)(ws + F_CNT);
        float*    prob  = (float*)(ws + F_PROB);

        hipLaunchKernelGGL(init_cnt, dim3(1), dim3(64), 0, stream, cnt);
        hipLaunchKernelGGL(gate_route, dim3(T_TOKENS / 4), dim3(256), 0, stream,
                           x, gw, gb, route, cnt, prob);
        hipLaunchKernelGGL(convert_x, dim3(T_TOKENS * DM / 1024), dim3(256), 0, stream, x, xb);
        hipLaunchKernelGGL((moe_gemm_v1<DM, DF, true>), dim3(NEXP * 16, DF / 128),
                           dim3(256), 0, stream, xb, W1, b1, route, cnt, prob,
                           h, (float*)nullptr);
        hipLaunchKernelGGL((moe_gemm_v1<DF, DM, false>), dim3(NEXP * 16, DM / 128),
                           dim3(256), 0, stream, h, W2, b2, route, cnt, prob,
                           (ushort*)nullptr, yc);
        hipLaunchKernelGGL(combine1, dim3(T_TOKENS * DM / 1024), dim3(256), 0, stream, yc, out);
    }
}

// Round 4
// 334.663 us; speedup vs baseline: 2.4172x; 1.0036x over previous
//
#include <hip/hip_runtime.h>
#include <stdint.h>

#define T_TOKENS 2048
#define DM 1024
#define DF 4096
#define NEXP 8
#define NSLOTS (T_TOKENS * 2)

typedef __bf16 bf16x8 __attribute__((ext_vector_type(8)));
typedef float f32x4 __attribute__((ext_vector_type(4)));

__device__ __forceinline__ ushort f2bf(float f) {
    union { float f; uint32_t u; } v; v.f = f;
    uint32_t r = v.u + 0x7FFFu + ((v.u >> 16) & 1u);
    return (ushort)(r >> 16);
}

__device__ __forceinline__ void gload16(const ushort* g, ushort* l) {
    __builtin_amdgcn_global_load_lds(
        (const __attribute__((address_space(1))) uint32_t*)g,
        (__attribute__((address_space(3))) uint32_t*)l,
        16, 0, 0);
}

// ---------------- init: zero expert counters ----------------
__global__ void init_cnt(uint32_t* cnt) {
    if (threadIdx.x < NEXP) cnt[threadIdx.x] = 0;
}

// ---------------- gating + routing: one wave per token ----------------
__global__ __launch_bounds__(256) void gate_route(
    const float* __restrict__ x, const float* __restrict__ gw,
    const float* __restrict__ gb,
    uint32_t* __restrict__ route, uint32_t* __restrict__ cnt,
    float* __restrict__ prob)
{
    const int w = threadIdx.x >> 6;
    const int lane = threadIdx.x & 63;
    const int t = blockIdx.x * 4 + w;
    float acc[NEXP];
#pragma unroll
    for (int e = 0; e < NEXP; ++e) acc[e] = 0.f;
    const float* xr = x + (size_t)t * DM;
#pragma unroll
    for (int j = 0; j < DM / 64; ++j) {
        const int d = j * 64 + lane;
        const float xv = xr[d];
        const float* g = gw + (size_t)d * NEXP;
#pragma unroll
        for (int e = 0; e < NEXP; ++e) acc[e] += xv * g[e];
    }
#pragma unroll
    for (int e = 0; e < NEXP; ++e) {
#pragma unroll
        for (int off = 32; off > 0; off >>= 1)
            acc[e] += __shfl_xor(acc[e], off);
        acc[e] += gb[e];
    }
    if (lane == 0) {
        int e0 = 0; float v0 = acc[0];
#pragma unroll
        for (int e = 1; e < NEXP; ++e) if (acc[e] > v0) { v0 = acc[e]; e0 = e; }
        int e1 = -1; float v1 = -1e30f;
#pragma unroll
        for (int e = 0; e < NEXP; ++e) if (e != e0 && acc[e] > v1) { v1 = acc[e]; e1 = e; }
        const float ex = expf(v1 - v0);
        const float inv = 1.f / (1.f + ex);
        prob[t * 2 + 0] = inv;
        prob[t * 2 + 1] = ex * inv;
        uint32_t pos = atomicAdd(&cnt[e0], 1u);
        route[e0 * T_TOKENS + pos] = (uint32_t)(t * 2);
        pos = atomicAdd(&cnt[e1], 1u);
        route[e1 * T_TOKENS + pos] = (uint32_t)(t * 2 + 1);
    }
}

// ---------------- x fp32 -> bf16 ----------------
__global__ __launch_bounds__(256) void convert_x(const float* __restrict__ x,
                                                 ushort* __restrict__ xb)
{
    const int i = (blockIdx.x * 256 + threadIdx.x) * 4;
    const float4 v = *reinterpret_cast<const float4*>(x + i);
    ushort4 o;
    o.x = f2bf(v.x); o.y = f2bf(v.y); o.z = f2bf(v.z); o.w = f2bf(v.w);
    *reinterpret_cast<ushort4*>(xb + i) = o;
}

// ---------------- W [E][K][N] f32 -> Wb [E][N][K] bf16 (64x64 tiles) ----------
template<int K, int N>
__global__ __launch_bounds__(256) void conv_transpose(const float* __restrict__ W,
                                                      ushort* __restrict__ Wb)
{
    const int e  = blockIdx.y;
    const int nt = blockIdx.x % (N / 64);
    const int kt = blockIdx.x / (N / 64);
    const int k0 = kt * 64, n0 = nt * 64;
    __shared__ ushort T[64][80];
    const int t = threadIdx.x;
    const int kr = t >> 4, nc = (t & 15) * 4;
    const float* src = W + ((size_t)e * K + k0 + kr) * N + n0 + nc;
#pragma unroll
    for (int i = 0; i < 4; ++i) {
        const float4 v = *reinterpret_cast<const float4*>(src + (size_t)i * 16 * N);
        T[nc + 0][kr + i * 16] = f2bf(v.x);
        T[nc + 1][kr + i * 16] = f2bf(v.y);
        T[nc + 2][kr + i * 16] = f2bf(v.z);
        T[nc + 3][kr + i * 16] = f2bf(v.w);
    }
    __syncthreads();
    const int r = t >> 2, c0 = t & 3;
    ushort* dst = Wb + ((size_t)e * N + n0 + r) * K + k0;
#pragma unroll
    for (int i = 0; i < 2; ++i) {
        const int c = c0 + i * 4;
        const uint4 v = *reinterpret_cast<const uint4*>(&T[r][c * 8]);
        *reinterpret_cast<uint4*>(dst + c * 8) = v;
    }
}

// ---------------- grouped expert GEMM v4: 2-phase + counted vmcnt (T4) -------
// A: bf16 rows gathered via route (stride KD); Wb: bf16 [E][ND][KD] (transposed)
// 128x128 tile, BK=64, double-buffered global_load_lds staging, st_16x32
// swizzle (inverse on source, forward on ds_read). 1D grid, n-tile fastest
// (NT % 8 == 0 so same-(e,nt) m-tiles share an XCD's L2 for the B panel).
// K-loop: STAGE(t+1) -> vmcnt(8) [t+1's loads stay in flight across barrier]
// -> s_barrier -> MFMA(t) -> s_barrier.  Never drains to 0 in steady state.
template<int KD, int ND, bool FIRST, int SPLIT, int NT>
__global__ __launch_bounds__(256, 2) void moe_gemm4(
    const ushort* __restrict__ Abuf,
    const ushort* __restrict__ Wb,
    const float* __restrict__ bias,
    const uint32_t* __restrict__ route,
    const uint32_t* __restrict__ cnt,
    const float* __restrict__ prob,
    ushort* __restrict__ hout,
    float* __restrict__ yout)
{
    const int bx = blockIdx.x;
    const int e  = bx / (16 * NT);
    const int mt = (bx / NT) & 15;
    const int nt = bx % NT;
    const uint32_t cntE = cnt[e];
    const int m0 = mt * 128;
    if ((uint32_t)m0 >= cntE) return;
    const int n0 = nt * 128;
    const int z  = (SPLIT > 1) ? (int)blockIdx.z : 0;
    const int kbeg = z * (KD / SPLIT);
    const int niter = (KD / SPLIT) / 64;

    __shared__ ushort As[2][128 * 64];
    __shared__ ushort Bs[2][128 * 64];
    __shared__ uint32_t s_route[128];

    const int tid = threadIdx.x;
    if (tid < 128) {
        const uint32_t idx = (uint32_t)(m0 + tid);
        s_route[tid] = (idx < cntE) ? route[e * T_TOKENS + idx] : 0xFFFFFFFFu;
    }
    __syncthreads();

    const int w = tid >> 6, l = tid & 63;

    // staging maps: 4 A-chunks + 4 B-chunks (16B each) per thread.
    // LDS dest linear (wave-uniform base + lane*16); global source carries the
    // inverse st_16x32 swizzle (XOR 32B-chunk bit with row bit2).
    const ushort* asrc[4];
    const ushort* bsrc[4];
#pragma unroll
    for (int i = 0; i < 4; ++i) {
        const int chunk = (w * 4 + i) * 64 + l;   // 0..1023
        const int row = chunk >> 3;
        const int c   = chunk & 7;
        const int cs  = c ^ (((row >> 2) & 1) << 1);
        const uint32_t s = s_route[row];
        const size_t ar = (s == 0xFFFFFFFFu) ? 0 : (FIRST ? (size_t)(s >> 1) : (size_t)s);
        asrc[i] = Abuf + ar * KD + cs * 8 + kbeg;
        bsrc[i] = Wb + ((size_t)e * ND + n0 + row) * KD + cs * 8 + kbeg;
    }

    f32x4 acc[4][4];
#pragma unroll
    for (int i = 0; i < 4; ++i)
#pragma unroll
        for (int j = 0; j < 4; ++j) acc[i][j] = (f32x4){0.f, 0.f, 0.f, 0.f};

    const int q = l & 15, g = l >> 4;
    const int wm = w >> 1, wn = w & 1;

    // swizzled fragment byte offsets (compile-time indexed)
    int aoff[4][2], boff[4][2];
#pragma unroll
    for (int mi = 0; mi < 4; ++mi)
#pragma unroll
        for (int ks = 0; ks < 2; ++ks) {
            int row = wm * 64 + mi * 16 + q;
            int b = row * 128 + ks * 64 + g * 16;
            b ^= ((b >> 9) & 1) << 5;
            aoff[mi][ks] = b;
            row = wn * 64 + mi * 16 + q;
            b = row * 128 + ks * 64 + g * 16;
            b ^= ((b >> 9) & 1) << 5;
            boff[mi][ks] = b;
        }

    ushort* const abase0 = &As[0][0];
    ushort* const bbase0 = &Bs[0][0];

    // prologue: stage tile 0 into buf 0 (8 loads in flight)
#pragma unroll
    for (int i = 0; i < 4; ++i) gload16(asrc[i], abase0 + (w * 4 + i) * 512);
#pragma unroll
    for (int i = 0; i < 4; ++i) gload16(bsrc[i], bbase0 + (w * 4 + i) * 512);

    int cur = 0;
    for (int t = 0; t < niter; ++t) {
        // issue next-tile prefetch into the other buffer
        if (t + 1 < niter) {
            ushort* ad = abase0 + (cur ^ 1) * (128 * 64) + (w * 4) * 512;
            ushort* bd = bbase0 + (cur ^ 1) * (128 * 64) + (w * 4) * 512;
            const int k1 = (t + 1) * 64;
#pragma unroll
            for (int i = 0; i < 4; ++i) gload16(asrc[i] + k1, ad + i * 512);
#pragma unroll
            for (int i = 0; i < 4; ++i) gload16(bsrc[i] + k1, bd + i * 512);
            // wait for tile t's 8 loads only; t+1's 8 stay in flight
            asm volatile("s_waitcnt vmcnt(8)" ::: "memory");
        } else {
            asm volatile("s_waitcnt vmcnt(0)" ::: "memory");
        }
        __builtin_amdgcn_s_barrier();
        __builtin_amdgcn_sched_barrier(0);

        // compute current tile
        const char* Ab = (const char*)(abase0 + cur * (128 * 64));
        const char* Bb = (const char*)(bbase0 + cur * (128 * 64));
#pragma unroll
        for (int ks = 0; ks < 2; ++ks) {
            bf16x8 af[4], bv[4];
#pragma unroll
            for (int mi = 0; mi < 4; ++mi)
                af[mi] = *reinterpret_cast<const bf16x8*>(Ab + aoff[mi][ks]);
#pragma unroll
            for (int ni = 0; ni < 4; ++ni)
                bv[ni] = *reinterpret_cast<const bf16x8*>(Bb + boff[ni][ks]);
            __builtin_amdgcn_s_setprio(1);
#pragma unroll
            for (int mi = 0; mi < 4; ++mi)
#pragma unroll
                for (int ni = 0; ni < 4; ++ni)
                    acc[mi][ni] = __builtin_amdgcn_mfma_f32_16x16x32_bf16(
                        af[mi], bv[ni], acc[mi][ni], 0, 0, 0);
            __builtin_amdgcn_s_setprio(0);
        }
        // all waves done reading buf[cur] before next iteration overwrites it
        __builtin_amdgcn_s_barrier();
        cur ^= 1;
    }

    // epilogue
    const float* brow = bias + (size_t)e * ND;
#pragma unroll
    for (int mi = 0; mi < 4; ++mi) {
#pragma unroll
        for (int ni = 0; ni < 4; ++ni) {
            const int gcol = n0 + wn * 64 + ni * 16 + q;
            const float bv = (SPLIT == 1 || z == 0) ? brow[gcol] : 0.f;
#pragma unroll
            for (int j = 0; j < 4; ++j) {
                const int row = wm * 64 + mi * 16 + g * 4 + j;
                if ((uint32_t)(m0 + row) < cntE) {
                    const uint32_t s = s_route[row];
                    float v = acc[mi][ni][j] + bv;
                    if (FIRST) {
                        v = fmaxf(v, 0.f);
                        hout[(size_t)s * ND + gcol] = f2bf(v);
                    } else {
                        yout[((size_t)z * NSLOTS + s) * ND + gcol] = v * prob[s];
                    }
                }
            }
        }
    }
}

// ---------------- combine (split-K=2): out[t] = sum of 4 yc rows ----------------
__global__ __launch_bounds__(256) void combine2(const float* __restrict__ yc,
                                                float* __restrict__ out)
{
    const int gid = blockIdx.x * 256 + threadIdx.x;   // over T*DM/4
    const int t = gid >> 8;
    const int dq = gid & 255;
    const float4* Y = reinterpret_cast<const float4*>(yc);
    const float4 a = Y[(size_t)(2 * t) * 256 + dq];
    const float4 b = Y[(size_t)(2 * t + 1) * 256 + dq];
    const float4 c = Y[((size_t)NSLOTS + 2 * t) * 256 + dq];
    const float4 d = Y[((size_t)NSLOTS + 2 * t + 1) * 256 + dq];
    const float4 o = { a.x + b.x + c.x + d.x, a.y + b.y + c.y + d.y,
                       a.z + b.z + c.z + d.z, a.w + b.w + c.w + d.w };
    reinterpret_cast<float4*>(out)[gid] = o;
}

// ================= fallback path (round-1, works in ~55 MB ws) =================
template<int KD, int ND, bool FIRST>
__global__ __launch_bounds__(256) void moe_gemm_v1(
    const ushort* __restrict__ Abuf, const float* __restrict__ W,
    const float* __restrict__ bias, const uint32_t* __restrict__ route,
    const uint32_t* __restrict__ cnt, const float* __restrict__ prob,
    ushort* __restrict__ hout, float* __restrict__ yout)
{
    const int e = blockIdx.x >> 4;
    const int mt = blockIdx.x & 15;
    const uint32_t cntE = cnt[e];
    const int m0 = mt * 128;
    if ((uint32_t)m0 >= cntE) return;
    const int n0 = blockIdx.y * 128;
    const int tid = threadIdx.x;
    __shared__ ushort Asm[128][40];
    __shared__ ushort Bsm[128][40];
    __shared__ uint32_t s_route[128];
    if (tid < 128) {
        const uint32_t idx = (uint32_t)(m0 + tid);
        s_route[tid] = (idx < cntE) ? route[e * T_TOKENS + idx] : 0xFFFFFFFFu;
    }
    __syncthreads();
    const int ar = tid >> 1, ah = tid & 1;
    const uint32_t s_a = s_route[ar];
    size_t arow = 0;
    if (s_a != 0xFFFFFFFFu) arow = FIRST ? (size_t)(s_a >> 1) : (size_t)s_a;
    const ushort* asrc = Abuf + arow * KD + ah * 16;
    const int c4 = tid & 31, kq = tid >> 5;
    const float* wbase = W + (size_t)e * KD * ND + (size_t)n0 + (size_t)c4 * 4;
    f32x4 acc[4][4];
#pragma unroll
    for (int i = 0; i < 4; ++i)
#pragma unroll
        for (int j = 0; j < 4; ++j) acc[i][j] = (f32x4){0.f, 0.f, 0.f, 0.f};
    const int lane = tid & 63, wv = tid >> 6;
    const int wm = wv >> 1, wn = wv & 1;
    const int q = lane & 15, g = lane >> 4;
    for (int k0 = 0; k0 < KD; k0 += 32) {
        {
            const uint4* src = reinterpret_cast<const uint4*>(asrc + k0);
            const uint4 v0 = src[0];
            const uint4 v1 = src[1];
            *reinterpret_cast<uint4*>(&Asm[ar][ah * 16]) = v0;
            *reinterpret_cast<uint4*>(&Asm[ar][ah * 16 + 8]) = v1;
        }
        {
            ushort vals[4][4];
#pragma unroll
            for (int r = 0; r < 4; ++r) {
                const float4 v = *reinterpret_cast<const float4*>(
                    wbase + (size_t)(k0 + kq * 4 + r) * ND);
                vals[r][0] = f2bf(v.x); vals[r][1] = f2bf(v.y);
                vals[r][2] = f2bf(v.z); vals[r][3] = f2bf(v.w);
            }
#pragma unroll
            for (int c = 0; c < 4; ++c) {
                const ushort4 o = { vals[0][c], vals[1][c], vals[2][c], vals[3][c] };
                *reinterpret_cast<ushort4*>(&Bsm[c4 * 4 + c][kq * 4]) = o;
            }
        }
        __syncthreads();
        bf16x8 af[4], bfr[4];
#pragma unroll
        for (int mi = 0; mi < 4; ++mi)
            af[mi] = *reinterpret_cast<const bf16x8*>(&Asm[wm * 64 + mi * 16 + q][g * 8]);
#pragma unroll
        for (int ni = 0; ni < 4; ++ni)
            bfr[ni] = *reinterpret_cast<const bf16x8*>(&Bsm[wn * 64 + ni * 16 + q][g * 8]);
#pragma unroll
        for (int mi = 0; mi < 4; ++mi)
#pragma unroll
            for (int ni = 0; ni < 4; ++ni)
                acc[mi][ni] = __builtin_amdgcn_mfma_f32_16x16x32_bf16(
                    af[mi], bfr[ni], acc[mi][ni], 0, 0, 0);
        __syncthreads();
    }
#pragma unroll
    for (int mi = 0; mi < 4; ++mi) {
#pragma unroll
        for (int ni = 0; ni < 4; ++ni) {
            const int gcol = n0 + wn * 64 + ni * 16 + q;
#pragma unroll
            for (int j = 0; j < 4; ++j) {
                const int row = wm * 64 + mi * 16 + g * 4 + j;
                if ((uint32_t)(m0 + row) < cntE) {
                    const uint32_t s = s_route[row];
                    float v = acc[mi][ni][j] + bias[e * ND + gcol];
                    if (FIRST) {
                        v = fmaxf(v, 0.f);
                        hout[(size_t)s * ND + gcol] = f2bf(v);
                    } else {
                        yout[(size_t)s * ND + gcol] = v * prob[s];
                    }
                }
            }
        }
    }
}

__global__ __launch_bounds__(256) void combine1(const float* __restrict__ yc,
                                                float* __restrict__ out)
{
    const int gid = blockIdx.x * 256 + threadIdx.x;
    const int t = gid >> 8;
    const int dq = gid & 255;
    const float4 va = reinterpret_cast<const float4*>(yc)[(size_t)(2 * t) * 256 + dq];
    const float4 vb = reinterpret_cast<const float4*>(yc)[(size_t)(2 * t + 1) * 256 + dq];
    const float4 o = { va.x + vb.x, va.y + vb.y, va.z + vb.z, va.w + vb.w };
    reinterpret_cast<float4*>(out)[gid] = o;
}

// ---------------- launch ----------------
extern "C" void kernel_launch(void* const* d_in, const int* in_sizes, int n_in,
                              void* d_out, int out_size, void* d_ws, size_t ws_size,
                              hipStream_t stream)
{
    const float* x  = (const float*)d_in[0];
    const float* gw = (const float*)d_in[1];
    const float* gb = (const float*)d_in[2];
    const float* W1 = (const float*)d_in[3];
    const float* b1 = (const float*)d_in[4];
    const float* W2 = (const float*)d_in[5];
    const float* b2 = (const float*)d_in[6];
    float* out = (float*)d_out;
    char* ws = (char*)d_ws;

    // ---- big layout (needs ~206 MB) ----
    const size_t OFF_XB    = 0;                        // 4 MiB
    const size_t OFF_H     = 4194304;                  // 32 MiB
    const size_t OFF_YC    = 37748736;                 // 32 MiB (2 splits)
    const size_t OFF_ROUTE = 71303168;                 // 64 KiB
    const size_t OFF_CNT   = 71368704;
    const size_t OFF_PROB  = 71368768;
    const size_t OFF_W1B   = 71385152;                 // 64 MiB
    const size_t OFF_W2B   = 138494016;                // 64 MiB
    const size_t NEED      = 205602880ull;

    if (ws_size >= NEED) {
        ushort*   xb    = (ushort*)(ws + OFF_XB);
        ushort*   h     = (ushort*)(ws + OFF_H);
        float*    yc    = (float*)(ws + OFF_YC);
        uint32_t* route = (uint32_t*)(ws + OFF_ROUTE);
        uint32_t* cnt   = (uint32_t*)(ws + OFF_CNT);
        float*    prob  = (float*)(ws + OFF_PROB);
        ushort*   w1b   = (ushort*)(ws + OFF_W1B);
        ushort*   w2b   = (ushort*)(ws + OFF_W2B);

        hipLaunchKernelGGL(init_cnt, dim3(1), dim3(64), 0, stream, cnt);
        hipLaunchKernelGGL(gate_route, dim3(T_TOKENS / 4), dim3(256), 0, stream,
                           x, gw, gb, route, cnt, prob);
        hipLaunchKernelGGL(convert_x, dim3(T_TOKENS * DM / 1024), dim3(256), 0, stream, x, xb);
        hipLaunchKernelGGL((conv_transpose<DM, DF>), dim3((DM / 64) * (DF / 64), NEXP),
                           dim3(256), 0, stream, W1, w1b);
        hipLaunchKernelGGL((conv_transpose<DF, DM>), dim3((DF / 64) * (DM / 64), NEXP),
                           dim3(256), 0, stream, W2, w2b);
        // GEMM1: 1D grid, n-tile fastest (NT=32)
        hipLaunchKernelGGL((moe_gemm4<DM, DF, true, 1, 32>),
                           dim3(NEXP * 16 * 32, 1, 1), dim3(256), 0, stream,
                           xb, w1b, b1, route, cnt, prob, h, (float*)nullptr);
        // GEMM2: split-K=2 in grid z (NT=8)
        hipLaunchKernelGGL((moe_gemm4<DF, DM, false, 2, 8>),
                           dim3(NEXP * 16 * 8, 1, 2), dim3(256), 0, stream,
                           h, w2b, b2, route, cnt, prob, (ushort*)nullptr, yc);
        hipLaunchKernelGGL(combine2, dim3(T_TOKENS * DM / 1024), dim3(256), 0, stream, yc, out);
    } else {
        // ---- fallback: round-1 layout (~55 MB) ----
        const size_t F_XB = 0, F_H = 4194304, F_YC = 37748736;
        const size_t F_ROUTE = 54525952, F_CNT = 54591488, F_PROB = 54591552;
        ushort*   xb    = (ushort*)(ws + F_XB);
        ushort*   h     = (ushort*)(ws + F_H);
        float*    yc    = (float*)(ws + F_YC);
        uint32_t* route = (uint32_t*)(ws + F_ROUTE);
        uint32_t* cnt   = (uint32_t*)(ws + F_CNT);
        float*    prob  = (float*)(ws + F_PROB);

        hipLaunchKernelGGL(init_cnt, dim3(1), dim3(64), 0, stream, cnt);
        hipLaunchKernelGGL(gate_route, dim3(T_TOKENS / 4), dim3(256), 0, stream,
                           x, gw, gb, route, cnt, prob);
        hipLaunchKernelGGL(convert_x, dim3(T_TOKENS * DM / 1024), dim3(256), 0, stream, x, xb);
        hipLaunchKernelGGL((moe_gemm_v1<DM, DF, true>), dim3(NEXP * 16, DF / 128),
                           dim3(256), 0, stream, xb, W1, b1, route, cnt, prob,
                           h, (float*)nullptr);
        hipLaunchKernelGGL((moe_gemm_v1<DF, DM, false>), dim3(NEXP * 16, DM / 128),
                           dim3(256), 0, stream, h, W2, b2, route, cnt, prob,
                           (ushort*)nullptr, yc);
        hipLaunchKernelGGL(combine1, dim3(T_TOKENS * DM / 1024), dim3(256), 0, stream, yc, out);
    }
}

// Round 5
// 315.714 us; speedup vs baseline: 2.5623x; 1.0600x over previous
//
#include <hip/hip_runtime.h>
#include <stdint.h>

#define T_TOKENS 2048
#define DM 1024
#define DF 4096
#define NEXP 8
#define NSLOTS (T_TOKENS * 2)

typedef __bf16 bf16x8 __attribute__((ext_vector_type(8)));
typedef float f32x4 __attribute__((ext_vector_type(4)));

__device__ __forceinline__ ushort f2bf(float f) {
    union { float f; uint32_t u; } v; v.f = f;
    uint32_t r = v.u + 0x7FFFu + ((v.u >> 16) & 1u);
    return (ushort)(r >> 16);
}

__device__ __forceinline__ void gload16(const ushort* g, ushort* l) {
    __builtin_amdgcn_global_load_lds(
        (const __attribute__((address_space(1))) uint32_t*)g,
        (__attribute__((address_space(3))) uint32_t*)l,
        16, 0, 0);
}

// ---------------- init: zero expert counters ----------------
__global__ void init_cnt(uint32_t* cnt) {
    if (threadIdx.x < NEXP) cnt[threadIdx.x] = 0;
}

// ---------------- gating + routing: one wave per token ----------------
__global__ __launch_bounds__(256) void gate_route(
    const float* __restrict__ x, const float* __restrict__ gw,
    const float* __restrict__ gb,
    uint32_t* __restrict__ route, uint32_t* __restrict__ cnt,
    float* __restrict__ prob)
{
    const int w = threadIdx.x >> 6;
    const int lane = threadIdx.x & 63;
    const int t = blockIdx.x * 4 + w;
    float acc[NEXP];
#pragma unroll
    for (int e = 0; e < NEXP; ++e) acc[e] = 0.f;
    const float* xr = x + (size_t)t * DM;
#pragma unroll
    for (int j = 0; j < DM / 64; ++j) {
        const int d = j * 64 + lane;
        const float xv = xr[d];
        const float* g = gw + (size_t)d * NEXP;
#pragma unroll
        for (int e = 0; e < NEXP; ++e) acc[e] += xv * g[e];
    }
#pragma unroll
    for (int e = 0; e < NEXP; ++e) {
#pragma unroll
        for (int off = 32; off > 0; off >>= 1)
            acc[e] += __shfl_xor(acc[e], off);
        acc[e] += gb[e];
    }
    if (lane == 0) {
        int e0 = 0; float v0 = acc[0];
#pragma unroll
        for (int e = 1; e < NEXP; ++e) if (acc[e] > v0) { v0 = acc[e]; e0 = e; }
        int e1 = -1; float v1 = -1e30f;
#pragma unroll
        for (int e = 0; e < NEXP; ++e) if (e != e0 && acc[e] > v1) { v1 = acc[e]; e1 = e; }
        const float ex = expf(v1 - v0);
        const float inv = 1.f / (1.f + ex);
        prob[t * 2 + 0] = inv;
        prob[t * 2 + 1] = ex * inv;
        uint32_t pos = atomicAdd(&cnt[e0], 1u);
        route[e0 * T_TOKENS + pos] = (uint32_t)(t * 2);
        pos = atomicAdd(&cnt[e1], 1u);
        route[e1 * T_TOKENS + pos] = (uint32_t)(t * 2 + 1);
    }
}

// ---------------- x fp32 -> bf16 ----------------
__global__ __launch_bounds__(256) void convert_x(const float* __restrict__ x,
                                                 ushort* __restrict__ xb)
{
    const int i = (blockIdx.x * 256 + threadIdx.x) * 4;
    const float4 v = *reinterpret_cast<const float4*>(x + i);
    ushort4 o;
    o.x = f2bf(v.x); o.y = f2bf(v.y); o.z = f2bf(v.z); o.w = f2bf(v.w);
    *reinterpret_cast<ushort4*>(xb + i) = o;
}

// ---------------- W [E][K][N] f32 -> Wb [E][N][K] bf16 (64x64 tiles) ----------
template<int K, int N>
__global__ __launch_bounds__(256) void conv_transpose(const float* __restrict__ W,
                                                      ushort* __restrict__ Wb)
{
    const int e  = blockIdx.y;
    const int nt = blockIdx.x % (N / 64);
    const int kt = blockIdx.x / (N / 64);
    const int k0 = kt * 64, n0 = nt * 64;
    __shared__ ushort T[64][80];
    const int t = threadIdx.x;
    const int kr = t >> 4, nc = (t & 15) * 4;
    const float* src = W + ((size_t)e * K + k0 + kr) * N + n0 + nc;
#pragma unroll
    for (int i = 0; i < 4; ++i) {
        const float4 v = *reinterpret_cast<const float4*>(src + (size_t)i * 16 * N);
        T[nc + 0][kr + i * 16] = f2bf(v.x);
        T[nc + 1][kr + i * 16] = f2bf(v.y);
        T[nc + 2][kr + i * 16] = f2bf(v.z);
        T[nc + 3][kr + i * 16] = f2bf(v.w);
    }
    __syncthreads();
    const int r = t >> 2, c0 = t & 3;
    ushort* dst = Wb + ((size_t)e * N + n0 + r) * K + k0;
#pragma unroll
    for (int i = 0; i < 2; ++i) {
        const int c = c0 + i * 4;
        const uint4 v = *reinterpret_cast<const uint4*>(&T[r][c * 8]);
        *reinterpret_cast<uint4*>(dst + c * 8) = v;
    }
}

// ---------------- grouped expert GEMM v5: BK=32, 4 blocks/CU ----------------
// A: bf16 rows gathered via route (stride KD); Wb: bf16 [E][ND][KD] (transposed)
// 128x128 tile, BK=32 double-buffered (32.5 KB LDS -> 4 blocks/CU), counted
// vmcnt(4), chunk-XOR swizzle (involution on source + ds_read). 1D grid,
// n-tile fastest (NT % 8 == 0 -> same (e,nt) B panel stays on one XCD's L2).
template<int KD, int ND, bool FIRST, int SPLIT, int NT>
__global__ __launch_bounds__(256, 4) void moe_gemm5(
    const ushort* __restrict__ Abuf,
    const ushort* __restrict__ Wb,
    const float* __restrict__ bias,
    const uint32_t* __restrict__ route,
    const uint32_t* __restrict__ cnt,
    const float* __restrict__ prob,
    ushort* __restrict__ hout,
    float* __restrict__ yout)
{
    const int bx = blockIdx.x;
    const int e  = bx / (16 * NT);
    const int mt = (bx / NT) & 15;
    const int nt = bx % NT;
    const uint32_t cntE = cnt[e];
    const int m0 = mt * 128;
    if ((uint32_t)m0 >= cntE) return;
    const int n0 = nt * 128;
    const int z  = (SPLIT > 1) ? (int)blockIdx.z : 0;
    const int kbeg = z * (KD / SPLIT);
    const int niter = (KD / SPLIT) / 32;

    __shared__ ushort As[2][128 * 32];
    __shared__ ushort Bs[2][128 * 32];
    __shared__ uint32_t s_route[128];

    const int tid = threadIdx.x;
    if (tid < 128) {
        const uint32_t idx = (uint32_t)(m0 + tid);
        s_route[tid] = (idx < cntE) ? route[e * T_TOKENS + idx] : 0xFFFFFFFFu;
    }
    __syncthreads();

    const int w = tid >> 6, l = tid & 63;

    // staging maps: 2 A-chunks + 2 B-chunks (16B each) per thread.
    // LDS dest linear (chunk*16B); global source carries the inverse swizzle:
    // a row is 64B = 4 chunks; chunk c holds global chunk c ^ ((row>>1)&3).
    const ushort* asrc[2];
    const ushort* bsrc[2];
#pragma unroll
    for (int i = 0; i < 2; ++i) {
        const int chunk = (w * 2 + i) * 64 + l;   // 0..511
        const int row = chunk >> 2;               // 0..127
        const int c   = chunk & 3;
        const int cs  = c ^ ((row >> 1) & 3);
        const uint32_t s = s_route[row];
        const size_t ar = (s == 0xFFFFFFFFu) ? 0 : (FIRST ? (size_t)(s >> 1) : (size_t)s);
        asrc[i] = Abuf + ar * KD + cs * 8 + kbeg;
        bsrc[i] = Wb + ((size_t)e * ND + n0 + row) * KD + cs * 8 + kbeg;
    }

    f32x4 acc[4][4];
#pragma unroll
    for (int i = 0; i < 4; ++i)
#pragma unroll
        for (int j = 0; j < 4; ++j) acc[i][j] = (f32x4){0.f, 0.f, 0.f, 0.f};

    const int q = l & 15, g = l >> 4;
    const int wm = w >> 1, wn = w & 1;

    // swizzled fragment byte offsets within a [128][32] bf16 buffer
    int aoff[4], boff[4];
#pragma unroll
    for (int mi = 0; mi < 4; ++mi) {
        int row = wm * 64 + mi * 16 + q;
        aoff[mi] = row * 64 + (g ^ ((row >> 1) & 3)) * 16;
        row = wn * 64 + mi * 16 + q;
        boff[mi] = row * 64 + (g ^ ((row >> 1) & 3)) * 16;
    }

    ushort* const abase0 = &As[0][0];
    ushort* const bbase0 = &Bs[0][0];

    // prologue: stage tile 0 into buf 0 (4 loads in flight per wave)
#pragma unroll
    for (int i = 0; i < 2; ++i) gload16(asrc[i], abase0 + (w * 2 + i) * 512);
#pragma unroll
    for (int i = 0; i < 2; ++i) gload16(bsrc[i], bbase0 + (w * 2 + i) * 512);

    int cur = 0;
    for (int t = 0; t < niter; ++t) {
        // issue next-tile prefetch into the other buffer
        if (t + 1 < niter) {
            ushort* ad = abase0 + (cur ^ 1) * (128 * 32) + (w * 2) * 512;
            ushort* bd = bbase0 + (cur ^ 1) * (128 * 32) + (w * 2) * 512;
            const int k1 = (t + 1) * 32;
#pragma unroll
            for (int i = 0; i < 2; ++i) gload16(asrc[i] + k1, ad + i * 512);
#pragma unroll
            for (int i = 0; i < 2; ++i) gload16(bsrc[i] + k1, bd + i * 512);
            // wait for tile t's 4 loads only; t+1's 4 stay in flight
            asm volatile("s_waitcnt vmcnt(4)" ::: "memory");
        } else {
            asm volatile("s_waitcnt vmcnt(0)" ::: "memory");
        }
        __builtin_amdgcn_s_barrier();
        __builtin_amdgcn_sched_barrier(0);

        // compute current tile
        const char* Ab = (const char*)(abase0 + cur * (128 * 32));
        const char* Bb = (const char*)(bbase0 + cur * (128 * 32));
        bf16x8 af[4], bv[4];
#pragma unroll
        for (int mi = 0; mi < 4; ++mi)
            af[mi] = *reinterpret_cast<const bf16x8*>(Ab + aoff[mi]);
#pragma unroll
        for (int ni = 0; ni < 4; ++ni)
            bv[ni] = *reinterpret_cast<const bf16x8*>(Bb + boff[ni]);
        __builtin_amdgcn_s_setprio(1);
#pragma unroll
        for (int mi = 0; mi < 4; ++mi)
#pragma unroll
            for (int ni = 0; ni < 4; ++ni)
                acc[mi][ni] = __builtin_amdgcn_mfma_f32_16x16x32_bf16(
                    af[mi], bv[ni], acc[mi][ni], 0, 0, 0);
        __builtin_amdgcn_s_setprio(0);
        // all waves done reading buf[cur] before next iteration overwrites it
        __builtin_amdgcn_s_barrier();
        cur ^= 1;
    }

    // epilogue
    const float* brow = bias + (size_t)e * ND;
#pragma unroll
    for (int mi = 0; mi < 4; ++mi) {
#pragma unroll
        for (int ni = 0; ni < 4; ++ni) {
            const int gcol = n0 + wn * 64 + ni * 16 + q;
            const float bv = (SPLIT == 1 || z == 0) ? brow[gcol] : 0.f;
#pragma unroll
            for (int j = 0; j < 4; ++j) {
                const int row = wm * 64 + mi * 16 + g * 4 + j;
                if ((uint32_t)(m0 + row) < cntE) {
                    const uint32_t s = s_route[row];
                    float v = acc[mi][ni][j] + bv;
                    if (FIRST) {
                        v = fmaxf(v, 0.f);
                        hout[(size_t)s * ND + gcol] = f2bf(v);
                    } else {
                        yout[((size_t)z * NSLOTS + s) * ND + gcol] = v * prob[s];
                    }
                }
            }
        }
    }
}

// ---------------- combine (split-K=4): out[t] = sum of 8 yc rows ----------------
__global__ __launch_bounds__(256) void combine4(const float* __restrict__ yc,
                                                float* __restrict__ out)
{
    const int gid = blockIdx.x * 256 + threadIdx.x;   // over T*DM/4
    const int t = gid >> 8;
    const int dq = gid & 255;
    const float4* Y = reinterpret_cast<const float4*>(yc);
    float4 o = {0.f, 0.f, 0.f, 0.f};
#pragma unroll
    for (int zz = 0; zz < 4; ++zz) {
#pragma unroll
        for (int k = 0; k < 2; ++k) {
            const float4 v = Y[((size_t)zz * NSLOTS + 2 * t + k) * 256 + dq];
            o.x += v.x; o.y += v.y; o.z += v.z; o.w += v.w;
        }
    }
    reinterpret_cast<float4*>(out)[gid] = o;
}

// ================= fallback path (round-1, works in ~55 MB ws) =================
template<int KD, int ND, bool FIRST>
__global__ __launch_bounds__(256) void moe_gemm_v1(
    const ushort* __restrict__ Abuf, const float* __restrict__ W,
    const float* __restrict__ bias, const uint32_t* __restrict__ route,
    const uint32_t* __restrict__ cnt, const float* __restrict__ prob,
    ushort* __restrict__ hout, float* __restrict__ yout)
{
    const int e = blockIdx.x >> 4;
    const int mt = blockIdx.x & 15;
    const uint32_t cntE = cnt[e];
    const int m0 = mt * 128;
    if ((uint32_t)m0 >= cntE) return;
    const int n0 = blockIdx.y * 128;
    const int tid = threadIdx.x;
    __shared__ ushort Asm[128][40];
    __shared__ ushort Bsm[128][40];
    __shared__ uint32_t s_route[128];
    if (tid < 128) {
        const uint32_t idx = (uint32_t)(m0 + tid);
        s_route[tid] = (idx < cntE) ? route[e * T_TOKENS + idx] : 0xFFFFFFFFu;
    }
    __syncthreads();
    const int ar = tid >> 1, ah = tid & 1;
    const uint32_t s_a = s_route[ar];
    size_t arow = 0;
    if (s_a != 0xFFFFFFFFu) arow = FIRST ? (size_t)(s_a >> 1) : (size_t)s_a;
    const ushort* asrc = Abuf + arow * KD + ah * 16;
    const int c4 = tid & 31, kq = tid >> 5;
    const float* wbase = W + (size_t)e * KD * ND + (size_t)n0 + (size_t)c4 * 4;
    f32x4 acc[4][4];
#pragma unroll
    for (int i = 0; i < 4; ++i)
#pragma unroll
        for (int j = 0; j < 4; ++j) acc[i][j] = (f32x4){0.f, 0.f, 0.f, 0.f};
    const int lane = tid & 63, wv = tid >> 6;
    const int wm = wv >> 1, wn = wv & 1;
    const int q = lane & 15, g = lane >> 4;
    for (int k0 = 0; k0 < KD; k0 += 32) {
        {
            const uint4* src = reinterpret_cast<const uint4*>(asrc + k0);
            const uint4 v0 = src[0];
            const uint4 v1 = src[1];
            *reinterpret_cast<uint4*>(&Asm[ar][ah * 16]) = v0;
            *reinterpret_cast<uint4*>(&Asm[ar][ah * 16 + 8]) = v1;
        }
        {
            ushort vals[4][4];
#pragma unroll
            for (int r = 0; r < 4; ++r) {
                const float4 v = *reinterpret_cast<const float4*>(
                    wbase + (size_t)(k0 + kq * 4 + r) * ND);
                vals[r][0] = f2bf(v.x); vals[r][1] = f2bf(v.y);
                vals[r][2] = f2bf(v.z); vals[r][3] = f2bf(v.w);
            }
#pragma unroll
            for (int c = 0; c < 4; ++c) {
                const ushort4 o = { vals[0][c], vals[1][c], vals[2][c], vals[3][c] };
                *reinterpret_cast<ushort4*>(&Bsm[c4 * 4 + c][kq * 4]) = o;
            }
        }
        __syncthreads();
        bf16x8 af[4], bfr[4];
#pragma unroll
        for (int mi = 0; mi < 4; ++mi)
            af[mi] = *reinterpret_cast<const bf16x8*>(&Asm[wm * 64 + mi * 16 + q][g * 8]);
#pragma unroll
        for (int ni = 0; ni < 4; ++ni)
            bfr[ni] = *reinterpret_cast<const bf16x8*>(&Bsm[wn * 64 + ni * 16 + q][g * 8]);
#pragma unroll
        for (int mi = 0; mi < 4; ++mi)
#pragma unroll
            for (int ni = 0; ni < 4; ++ni)
                acc[mi][ni] = __builtin_amdgcn_mfma_f32_16x16x32_bf16(
                    af[mi], bfr[ni], acc[mi][ni], 0, 0, 0);
        __syncthreads();
    }
#pragma unroll
    for (int mi = 0; mi < 4; ++mi) {
#pragma unroll
        for (int ni = 0; ni < 4; ++ni) {
            const int gcol = n0 + wn * 64 + ni * 16 + q;
#pragma unroll
            for (int j = 0; j < 4; ++j) {
                const int row = wm * 64 + mi * 16 + g * 4 + j;
                if ((uint32_t)(m0 + row) < cntE) {
                    const uint32_t s = s_route[row];
                    float v = acc[mi][ni][j] + bias[e * ND + gcol];
                    if (FIRST) {
                        v = fmaxf(v, 0.f);
                        hout[(size_t)s * ND + gcol] = f2bf(v);
                    } else {
                        yout[(size_t)s * ND + gcol] = v * prob[s];
                    }
                }
            }
        }
    }
}

__global__ __launch_bounds__(256) void combine1(const float* __restrict__ yc,
                                                float* __restrict__ out)
{
    const int gid = blockIdx.x * 256 + threadIdx.x;
    const int t = gid >> 8;
    const int dq = gid & 255;
    const float4 va = reinterpret_cast<const float4*>(yc)[(size_t)(2 * t) * 256 + dq];
    const float4 vb = reinterpret_cast<const float4*>(yc)[(size_t)(2 * t + 1) * 256 + dq];
    const float4 o = { va.x + vb.x, va.y + vb.y, va.z + vb.z, va.w + vb.w };
    reinterpret_cast<float4*>(out)[gid] = o;
}

// ---------------- launch ----------------
extern "C" void kernel_launch(void* const* d_in, const int* in_sizes, int n_in,
                              void* d_out, int out_size, void* d_ws, size_t ws_size,
                              hipStream_t stream)
{
    const float* x  = (const float*)d_in[0];
    const float* gw = (const float*)d_in[1];
    const float* gb = (const float*)d_in[2];
    const float* W1 = (const float*)d_in[3];
    const float* b1 = (const float*)d_in[4];
    const float* W2 = (const float*)d_in[5];
    const float* b2 = (const float*)d_in[6];
    float* out = (float*)d_out;
    char* ws = (char*)d_ws;

    // ---- big layout (~173 MB; yc split-K=4 partials ALIAS w1b, dead after GEMM1)
    const size_t OFF_XB    = 0;                        // 4 MiB
    const size_t OFF_H     = 4194304;                  // 32 MiB
    const size_t OFF_ROUTE = 37748736;                 // 64 KiB
    const size_t OFF_CNT   = 37814272;                 // 64 B
    const size_t OFF_PROB  = 37814336;                 // 16 KiB
    const size_t OFF_W1B   = 38797312;                 // 64 MiB (aliased by yc)
    const size_t OFF_W2B   = 105906176;                // 64 MiB
    const size_t OFF_YC    = OFF_W1B;                  // 64 MiB (4 z-splits)
    const size_t NEED      = 173015040ull;

    if (ws_size >= NEED) {
        ushort*   xb    = (ushort*)(ws + OFF_XB);
        ushort*   h     = (ushort*)(ws + OFF_H);
        float*    yc    = (float*)(ws + OFF_YC);
        uint32_t* route = (uint32_t*)(ws + OFF_ROUTE);
        uint32_t* cnt   = (uint32_t*)(ws + OFF_CNT);
        float*    prob  = (float*)(ws + OFF_PROB);
        ushort*   w1b   = (ushort*)(ws + OFF_W1B);
        ushort*   w2b   = (ushort*)(ws + OFF_W2B);

        hipLaunchKernelGGL(init_cnt, dim3(1), dim3(64), 0, stream, cnt);
        hipLaunchKernelGGL(gate_route, dim3(T_TOKENS / 4), dim3(256), 0, stream,
                           x, gw, gb, route, cnt, prob);
        hipLaunchKernelGGL(convert_x, dim3(T_TOKENS * DM / 1024), dim3(256), 0, stream, x, xb);
        hipLaunchKernelGGL((conv_transpose<DM, DF>), dim3((DM / 64) * (DF / 64), NEXP),
                           dim3(256), 0, stream, W1, w1b);
        hipLaunchKernelGGL((conv_transpose<DF, DM>), dim3((DF / 64) * (DM / 64), NEXP),
                           dim3(256), 0, stream, W2, w2b);
        // GEMM1: 1D grid, n-tile fastest (NT=32)
        hipLaunchKernelGGL((moe_gemm5<DM, DF, true, 1, 32>),
                           dim3(NEXP * 16 * 32, 1, 1), dim3(256), 0, stream,
                           xb, w1b, b1, route, cnt, prob, h, (float*)nullptr);
        // GEMM2: split-K=4 in grid z (NT=8); yc aliases w1b (w1b dead now)
        hipLaunchKernelGGL((moe_gemm5<DF, DM, false, 4, 8>),
                           dim3(NEXP * 16 * 8, 1, 4), dim3(256), 0, stream,
                           h, w2b, b2, route, cnt, prob, (ushort*)nullptr, yc);
        hipLaunchKernelGGL(combine4, dim3(T_TOKENS * DM / 1024), dim3(256), 0, stream, yc, out);
    } else {
        // ---- fallback: round-1 layout (~55 MB) ----
        const size_t F_XB = 0, F_H = 4194304, F_YC = 37748736;
        const size_t F_ROUTE = 54525952, F_CNT = 54591488, F_PROB = 54591552;
        ushort*   xb    = (ushort*)(ws + F_XB);
        ushort*   h     = (ushort*)(ws + F_H);
        float*    yc    = (float*)(ws + F_YC);
        uint32_t* route = (uint32_t*)(ws + F_ROUTE);
        uint32_t* cnt   = (uint32_t*)(ws + F_CNT);
        float*    prob  = (float*)(ws + F_PROB);

        hipLaunchKernelGGL(init_cnt, dim3(1), dim3(64), 0, stream, cnt);
        hipLaunchKernelGGL(gate_route, dim3(T_TOKENS / 4), dim3(256), 0, stream,
                           x, gw, gb, route, cnt, prob);
        hipLaunchKernelGGL(convert_x, dim3(T_TOKENS * DM / 1024), dim3(256), 0, stream, x, xb);
        hipLaunchKernelGGL((moe_gemm_v1<DM, DF, true>), dim3(NEXP * 16, DF / 128),
                           dim3(256), 0, stream, xb, W1, b1, route, cnt, prob,
                           h, (float*)nullptr);
        hipLaunchKernelGGL((moe_gemm_v1<DF, DM, false>), dim3(NEXP * 16, DM / 128),
                           dim3(256), 0, stream, h, W2, b2, route, cnt, prob,
                           (ushort*)nullptr, yc);
        hipLaunchKernelGGL(combine1, dim3(T_TOKENS * DM / 1024), dim3(256), 0, stream, yc, out);
    }
}

// Round 6
// 305.454 us; speedup vs baseline: 2.6483x; 1.0336x over previous
//
#include <hip/hip_runtime.h>
#include <stdint.h>

#define T_TOKENS 2048
#define DM 1024
#define DF 4096
#define NEXP 8
#define NSLOTS (T_TOKENS * 2)
#define HROWS (NSLOTS + 128)   // slack for unguarded tail A-reads

typedef __bf16 bf16x8 __attribute__((ext_vector_type(8)));
typedef float f32x4 __attribute__((ext_vector_type(4)));

__device__ __forceinline__ ushort f2bf(float f) {
    union { float f; uint32_t u; } v; v.f = f;
    uint32_t r = v.u + 0x7FFFu + ((v.u >> 16) & 1u);
    return (ushort)(r >> 16);
}

__device__ __forceinline__ void gload16(const ushort* g, ushort* l) {
    __builtin_amdgcn_global_load_lds(
        (const __attribute__((address_space(1))) uint32_t*)g,
        (__attribute__((address_space(3))) uint32_t*)l,
        16, 0, 0);
}

// ---------------- init: zero expert counters ----------------
__global__ void init_cnt(uint32_t* cnt) {
    if (threadIdx.x < NEXP) cnt[threadIdx.x] = 0;
}

// ---------------- gating + routing: one wave per token ----------------
__global__ __launch_bounds__(256) void gate_route(
    const float* __restrict__ x, const float* __restrict__ gw,
    const float* __restrict__ gb,
    uint32_t* __restrict__ route, uint32_t* __restrict__ cnt,
    float* __restrict__ prob, uint32_t* __restrict__ epk)
{
    const int w = threadIdx.x >> 6;
    const int lane = threadIdx.x & 63;
    const int t = blockIdx.x * 4 + w;
    float acc[NEXP];
#pragma unroll
    for (int e = 0; e < NEXP; ++e) acc[e] = 0.f;
    const float* xr = x + (size_t)t * DM;
#pragma unroll
    for (int j = 0; j < DM / 64; ++j) {
        const int d = j * 64 + lane;
        const float xv = xr[d];
        const float* g = gw + (size_t)d * NEXP;
#pragma unroll
        for (int e = 0; e < NEXP; ++e) acc[e] += xv * g[e];
    }
#pragma unroll
    for (int e = 0; e < NEXP; ++e) {
#pragma unroll
        for (int off = 32; off > 0; off >>= 1)
            acc[e] += __shfl_xor(acc[e], off);
        acc[e] += gb[e];
    }
    if (lane == 0) {
        int e0 = 0; float v0 = acc[0];
#pragma unroll
        for (int e = 1; e < NEXP; ++e) if (acc[e] > v0) { v0 = acc[e]; e0 = e; }
        int e1 = -1; float v1 = -1e30f;
#pragma unroll
        for (int e = 0; e < NEXP; ++e) if (e != e0 && acc[e] > v1) { v1 = acc[e]; e1 = e; }
        const float ex = expf(v1 - v0);
        const float inv = 1.f / (1.f + ex);
        prob[t * 2 + 0] = inv;
        prob[t * 2 + 1] = ex * inv;
        uint32_t pos = atomicAdd(&cnt[e0], 1u);
        route[e0 * T_TOKENS + pos] = (uint32_t)(t * 2);
        epk[t * 2] = ((uint32_t)e0 << 16) | pos;
        pos = atomicAdd(&cnt[e1], 1u);
        route[e1 * T_TOKENS + pos] = (uint32_t)(t * 2 + 1);
        epk[t * 2 + 1] = ((uint32_t)e1 << 16) | pos;
    }
}

// ---------------- exclusive prefix over the 8 counts ----------------
__global__ void prefix_offs(const uint32_t* __restrict__ cnt,
                            uint32_t* __restrict__ offs)
{
    if (threadIdx.x == 0) {
        uint32_t a = 0;
#pragma unroll
        for (int e = 0; e < NEXP; ++e) { offs[e] = a; a += cnt[e]; }
        offs[NEXP] = a;
    }
}

// ---------------- x fp32 -> bf16 ----------------
__global__ __launch_bounds__(256) void convert_x(const float* __restrict__ x,
                                                 ushort* __restrict__ xb)
{
    const int i = (blockIdx.x * 256 + threadIdx.x) * 4;
    const float4 v = *reinterpret_cast<const float4*>(x + i);
    ushort4 o;
    o.x = f2bf(v.x); o.y = f2bf(v.y); o.z = f2bf(v.z); o.w = f2bf(v.w);
    *reinterpret_cast<ushort4*>(xb + i) = o;
}

// ---------------- W [E][K][N] f32 -> Wb [E][N][K] bf16 (64x64 tiles) ----------
template<int K, int N>
__global__ __launch_bounds__(256) void conv_transpose(const float* __restrict__ W,
                                                      ushort* __restrict__ Wb)
{
    const int e  = blockIdx.y;
    const int nt = blockIdx.x % (N / 64);
    const int kt = blockIdx.x / (N / 64);
    const int k0 = kt * 64, n0 = nt * 64;
    __shared__ ushort T[64][80];
    const int t = threadIdx.x;
    const int kr = t >> 4, nc = (t & 15) * 4;
    const float* src = W + ((size_t)e * K + k0 + kr) * N + n0 + nc;
#pragma unroll
    for (int i = 0; i < 4; ++i) {
        const float4 v = *reinterpret_cast<const float4*>(src + (size_t)i * 16 * N);
        T[nc + 0][kr + i * 16] = f2bf(v.x);
        T[nc + 1][kr + i * 16] = f2bf(v.y);
        T[nc + 2][kr + i * 16] = f2bf(v.z);
        T[nc + 3][kr + i * 16] = f2bf(v.w);
    }
    __syncthreads();
    const int r = t >> 2, c0 = t & 3;
    ushort* dst = Wb + ((size_t)e * N + n0 + r) * K + k0;
#pragma unroll
    for (int i = 0; i < 2; ++i) {
        const int c = c0 + i * 4;
        const uint4 v = *reinterpret_cast<const uint4*>(&T[r][c * 8]);
        *reinterpret_cast<uint4*>(dst + c * 8) = v;
    }
}

// ---------------- grouped expert GEMM v6: expert-order intermediates ---------
// FIRST: A = xb gathered via route; out h[offs[e]+idx] = bf16(relu(xW1+b1)*p)
// else:  A = h[offs[e]+idx] (contiguous, no gather); out yc[z][offs[e]+idx]
// 128x128 tile, BK=32 double-buffered, counted vmcnt(4), chunk-XOR swizzle.
template<int KD, int ND, bool FIRST, int SPLIT, int NT>
__global__ __launch_bounds__(256, 4) void moe_gemm6(
    const ushort* __restrict__ Abuf,
    const ushort* __restrict__ Wb,
    const float* __restrict__ bias,
    const uint32_t* __restrict__ route,
    const uint32_t* __restrict__ cnt,
    const uint32_t* __restrict__ offs,
    const float* __restrict__ prob,
    ushort* __restrict__ hout,
    float* __restrict__ yout)
{
    const int bx = blockIdx.x;
    const int e  = bx / (16 * NT);
    const int mt = (bx / NT) & 15;
    const int nt = bx % NT;
    const uint32_t cntE = cnt[e];
    const int m0 = mt * 128;
    if ((uint32_t)m0 >= cntE) return;
    const uint32_t hb = offs[e];
    const int n0 = nt * 128;
    const int z  = (SPLIT > 1) ? (int)blockIdx.z : 0;
    const int kbeg = z * (KD / SPLIT);
    const int niter = (KD / SPLIT) / 32;

    __shared__ ushort As[2][128 * 32];
    __shared__ ushort Bs[2][128 * 32];
    __shared__ uint32_t s_route[128];
    __shared__ float s_p[128];

    const int tid = threadIdx.x;
    if (FIRST) {
        if (tid < 128) {
            const uint32_t idx = (uint32_t)(m0 + tid);
            const uint32_t s = (idx < cntE) ? route[e * T_TOKENS + idx] : 0u;
            s_route[tid] = s;
            s_p[tid] = prob[s];
        }
        __syncthreads();
    }

    const int w = tid >> 6, l = tid & 63;

    // staging maps: 2 A-chunks + 2 B-chunks (16B each) per thread.
    // LDS dest linear; global source carries the inverse swizzle
    // (row = 64B = 4 chunks; chunk c holds global chunk c ^ ((row>>1)&3)).
    const ushort* asrc[2];
    const ushort* bsrc[2];
#pragma unroll
    for (int i = 0; i < 2; ++i) {
        const int chunk = (w * 2 + i) * 64 + l;   // 0..511
        const int row = chunk >> 2;               // 0..127
        const int c   = chunk & 3;
        const int cs  = c ^ ((row >> 1) & 3);
        size_t arow;
        if (FIRST) arow = (size_t)(s_route[row] >> 1);     // token id
        else       arow = (size_t)(hb + m0 + row);         // expert-order h row
        asrc[i] = Abuf + arow * KD + cs * 8 + kbeg;
        bsrc[i] = Wb + ((size_t)e * ND + n0 + row) * KD + cs * 8 + kbeg;
    }

    f32x4 acc[4][4];
#pragma unroll
    for (int i = 0; i < 4; ++i)
#pragma unroll
        for (int j = 0; j < 4; ++j) acc[i][j] = (f32x4){0.f, 0.f, 0.f, 0.f};

    const int q = l & 15, g = l >> 4;
    const int wm = w >> 1, wn = w & 1;

    // swizzled fragment byte offsets within a [128][32] bf16 buffer
    int aoff[4], boff[4];
#pragma unroll
    for (int mi = 0; mi < 4; ++mi) {
        int row = wm * 64 + mi * 16 + q;
        aoff[mi] = row * 64 + (g ^ ((row >> 1) & 3)) * 16;
        row = wn * 64 + mi * 16 + q;
        boff[mi] = row * 64 + (g ^ ((row >> 1) & 3)) * 16;
    }

    ushort* const abase0 = &As[0][0];
    ushort* const bbase0 = &Bs[0][0];

    // prologue: stage tile 0 into buf 0 (4 loads in flight per wave)
#pragma unroll
    for (int i = 0; i < 2; ++i) gload16(asrc[i], abase0 + (w * 2 + i) * 512);
#pragma unroll
    for (int i = 0; i < 2; ++i) gload16(bsrc[i], bbase0 + (w * 2 + i) * 512);

    int cur = 0;
    for (int t = 0; t < niter; ++t) {
        if (t + 1 < niter) {
            ushort* ad = abase0 + (cur ^ 1) * (128 * 32) + (w * 2) * 512;
            ushort* bd = bbase0 + (cur ^ 1) * (128 * 32) + (w * 2) * 512;
            const int k1 = (t + 1) * 32;
#pragma unroll
            for (int i = 0; i < 2; ++i) gload16(asrc[i] + k1, ad + i * 512);
#pragma unroll
            for (int i = 0; i < 2; ++i) gload16(bsrc[i] + k1, bd + i * 512);
            asm volatile("s_waitcnt vmcnt(4)" ::: "memory");
        } else {
            asm volatile("s_waitcnt vmcnt(0)" ::: "memory");
        }
        __builtin_amdgcn_s_barrier();
        __builtin_amdgcn_sched_barrier(0);

        const char* Ab = (const char*)(abase0 + cur * (128 * 32));
        const char* Bb = (const char*)(bbase0 + cur * (128 * 32));
        bf16x8 af[4], bv[4];
#pragma unroll
        for (int mi = 0; mi < 4; ++mi)
            af[mi] = *reinterpret_cast<const bf16x8*>(Ab + aoff[mi]);
#pragma unroll
        for (int ni = 0; ni < 4; ++ni)
            bv[ni] = *reinterpret_cast<const bf16x8*>(Bb + boff[ni]);
        __builtin_amdgcn_s_setprio(1);
#pragma unroll
        for (int mi = 0; mi < 4; ++mi)
#pragma unroll
            for (int ni = 0; ni < 4; ++ni)
                acc[mi][ni] = __builtin_amdgcn_mfma_f32_16x16x32_bf16(
                    af[mi], bv[ni], acc[mi][ni], 0, 0, 0);
        __builtin_amdgcn_s_setprio(0);
        __builtin_amdgcn_s_barrier();
        cur ^= 1;
    }

    // epilogue
#pragma unroll
    for (int mi = 0; mi < 4; ++mi) {
#pragma unroll
        for (int ni = 0; ni < 4; ++ni) {
            const int gcol = n0 + wn * 64 + ni * 16 + q;
#pragma unroll
            for (int j = 0; j < 4; ++j) {
                const int row = wm * 64 + mi * 16 + g * 4 + j;
                if ((uint32_t)(m0 + row) < cntE) {
                    const size_t grow = (size_t)(hb + m0 + row);
                    if (FIRST) {
                        float v = acc[mi][ni][j] + bias[e * ND + gcol];
                        v = fmaxf(v, 0.f) * s_p[row];
                        hout[grow * ND + gcol] = f2bf(v);
                    } else {
                        yout[((size_t)z * NSLOTS + grow) * ND + gcol] = acc[mi][ni][j];
                    }
                }
            }
        }
    }
}

// ------- combine: out[t] = p0*b2[e0] + p1*b2[e1] + sum_z (yc[z][r0]+yc[z][r1])
__global__ __launch_bounds__(256) void combine5(
    const float* __restrict__ yc, const uint32_t* __restrict__ epk,
    const uint32_t* __restrict__ offs, const float* __restrict__ prob,
    const float* __restrict__ b2, float* __restrict__ out)
{
    const int gid = blockIdx.x * 256 + threadIdx.x;   // over T*DM/4
    const int t = gid >> 8;
    const int dq = gid & 255;
    const uint32_t p0 = epk[2 * t], p1 = epk[2 * t + 1];
    const uint32_t e0 = p0 >> 16, e1 = p1 >> 16;
    const uint32_t r0 = offs[e0] + (p0 & 0xFFFFu);
    const uint32_t r1 = offs[e1] + (p1 & 0xFFFFu);
    const float w0 = prob[2 * t], w1 = prob[2 * t + 1];
    const float4 bb0 = reinterpret_cast<const float4*>(b2 + (size_t)e0 * DM)[dq];
    const float4 bb1 = reinterpret_cast<const float4*>(b2 + (size_t)e1 * DM)[dq];
    float4 o = { w0 * bb0.x + w1 * bb1.x, w0 * bb0.y + w1 * bb1.y,
                 w0 * bb0.z + w1 * bb1.z, w0 * bb0.w + w1 * bb1.w };
    const float4* Y = reinterpret_cast<const float4*>(yc);
#pragma unroll
    for (int zz = 0; zz < 4; ++zz) {
        const float4 a = Y[((size_t)zz * NSLOTS + r0) * 256 + dq];
        const float4 b = Y[((size_t)zz * NSLOTS + r1) * 256 + dq];
        o.x += a.x + b.x; o.y += a.y + b.y; o.z += a.z + b.z; o.w += a.w + b.w;
    }
    reinterpret_cast<float4*>(out)[gid] = o;
}

// ================= fallback path (round-1, works in ~55 MB ws) =================
template<int KD, int ND, bool FIRST>
__global__ __launch_bounds__(256) void moe_gemm_v1(
    const ushort* __restrict__ Abuf, const float* __restrict__ W,
    const float* __restrict__ bias, const uint32_t* __restrict__ route,
    const uint32_t* __restrict__ cnt, const float* __restrict__ prob,
    ushort* __restrict__ hout, float* __restrict__ yout)
{
    const int e = blockIdx.x >> 4;
    const int mt = blockIdx.x & 15;
    const uint32_t cntE = cnt[e];
    const int m0 = mt * 128;
    if ((uint32_t)m0 >= cntE) return;
    const int n0 = blockIdx.y * 128;
    const int tid = threadIdx.x;
    __shared__ ushort Asm[128][40];
    __shared__ ushort Bsm[128][40];
    __shared__ uint32_t s_route[128];
    if (tid < 128) {
        const uint32_t idx = (uint32_t)(m0 + tid);
        s_route[tid] = (idx < cntE) ? route[e * T_TOKENS + idx] : 0xFFFFFFFFu;
    }
    __syncthreads();
    const int ar = tid >> 1, ah = tid & 1;
    const uint32_t s_a = s_route[ar];
    size_t arow = 0;
    if (s_a != 0xFFFFFFFFu) arow = FIRST ? (size_t)(s_a >> 1) : (size_t)s_a;
    const ushort* asrc = Abuf + arow * KD + ah * 16;
    const int c4 = tid & 31, kq = tid >> 5;
    const float* wbase = W + (size_t)e * KD * ND + (size_t)n0 + (size_t)c4 * 4;
    f32x4 acc[4][4];
#pragma unroll
    for (int i = 0; i < 4; ++i)
#pragma unroll
        for (int j = 0; j < 4; ++j) acc[i][j] = (f32x4){0.f, 0.f, 0.f, 0.f};
    const int lane = tid & 63, wv = tid >> 6;
    const int wm = wv >> 1, wn = wv & 1;
    const int q = lane & 15, g = lane >> 4;
    for (int k0 = 0; k0 < KD; k0 += 32) {
        {
            const uint4* src = reinterpret_cast<const uint4*>(asrc + k0);
            const uint4 v0 = src[0];
            const uint4 v1 = src[1];
            *reinterpret_cast<uint4*>(&Asm[ar][ah * 16]) = v0;
            *reinterpret_cast<uint4*>(&Asm[ar][ah * 16 + 8]) = v1;
        }
        {
            ushort vals[4][4];
#pragma unroll
            for (int r = 0; r < 4; ++r) {
                const float4 v = *reinterpret_cast<const float4*>(
                    wbase + (size_t)(k0 + kq * 4 + r) * ND);
                vals[r][0] = f2bf(v.x); vals[r][1] = f2bf(v.y);
                vals[r][2] = f2bf(v.z); vals[r][3] = f2bf(v.w);
            }
#pragma unroll
            for (int c = 0; c < 4; ++c) {
                const ushort4 o = { vals[0][c], vals[1][c], vals[2][c], vals[3][c] };
                *reinterpret_cast<ushort4*>(&Bsm[c4 * 4 + c][kq * 4]) = o;
            }
        }
        __syncthreads();
        bf16x8 af[4], bfr[4];
#pragma unroll
        for (int mi = 0; mi < 4; ++mi)
            af[mi] = *reinterpret_cast<const bf16x8*>(&Asm[wm * 64 + mi * 16 + q][g * 8]);
#pragma unroll
        for (int ni = 0; ni < 4; ++ni)
            bfr[ni] = *reinterpret_cast<const bf16x8*>(&Bsm[wn * 64 + ni * 16 + q][g * 8]);
#pragma unroll
        for (int mi = 0; mi < 4; ++mi)
#pragma unroll
            for (int ni = 0; ni < 4; ++ni)
                acc[mi][ni] = __builtin_amdgcn_mfma_f32_16x16x32_bf16(
                    af[mi], bfr[ni], acc[mi][ni], 0, 0, 0);
        __syncthreads();
    }
#pragma unroll
    for (int mi = 0; mi < 4; ++mi) {
#pragma unroll
        for (int ni = 0; ni < 4; ++ni) {
            const int gcol = n0 + wn * 64 + ni * 16 + q;
#pragma unroll
            for (int j = 0; j < 4; ++j) {
                const int row = wm * 64 + mi * 16 + g * 4 + j;
                if ((uint32_t)(m0 + row) < cntE) {
                    const uint32_t s = s_route[row];
                    float v = acc[mi][ni][j] + bias[e * ND + gcol];
                    if (FIRST) {
                        v = fmaxf(v, 0.f);
                        hout[(size_t)s * ND + gcol] = f2bf(v);
                    } else {
                        yout[(size_t)s * ND + gcol] = v * prob[s];
                    }
                }
            }
        }
    }
}

__global__ __launch_bounds__(256) void combine1(const float* __restrict__ yc,
                                                float* __restrict__ out)
{
    const int gid = blockIdx.x * 256 + threadIdx.x;
    const int t = gid >> 8;
    const int dq = gid & 255;
    const float4 va = reinterpret_cast<const float4*>(yc)[(size_t)(2 * t) * 256 + dq];
    const float4 vb = reinterpret_cast<const float4*>(yc)[(size_t)(2 * t + 1) * 256 + dq];
    const float4 o = { va.x + vb.x, va.y + vb.y, va.z + vb.z, va.w + vb.w };
    reinterpret_cast<float4*>(out)[gid] = o;
}

// ---------------- launch ----------------
extern "C" void kernel_launch(void* const* d_in, const int* in_sizes, int n_in,
                              void* d_out, int out_size, void* d_ws, size_t ws_size,
                              hipStream_t stream)
{
    const float* x  = (const float*)d_in[0];
    const float* gw = (const float*)d_in[1];
    const float* gb = (const float*)d_in[2];
    const float* W1 = (const float*)d_in[3];
    const float* b1 = (const float*)d_in[4];
    const float* W2 = (const float*)d_in[5];
    const float* b2 = (const float*)d_in[6];
    float* out = (float*)d_out;
    char* ws = (char*)d_ws;

    // ---- big layout (~168 MB; yc aliases w1b which is dead after GEMM1) ----
    const size_t OFF_XB    = 0;                        // 4 MiB
    const size_t OFF_H     = 4194304;                  // HROWS*4096*2 = 33 MiB
    const size_t OFF_ROUTE = 38797312;                 // 64 KiB
    const size_t OFF_CNT   = 38862848;                 // 64 B
    const size_t OFF_OFFS  = 38862912;                 // 64 B
    const size_t OFF_PROB  = 38862976;                 // 16 KiB
    const size_t OFF_EPK   = 38879360;                 // 16 KiB
    const size_t OFF_W1B   = 41943040;                 // 64 MiB (aliased by yc)
    const size_t OFF_W2B   = 109051904;                // 64 MiB
    const size_t OFF_YC    = OFF_W1B;                  // 64 MiB (4 z-splits)
    const size_t NEED      = 176160768ull;

    if (ws_size >= NEED) {
        ushort*   xb    = (ushort*)(ws + OFF_XB);
        ushort*   h     = (ushort*)(ws + OFF_H);
        float*    yc    = (float*)(ws + OFF_YC);
        uint32_t* route = (uint32_t*)(ws + OFF_ROUTE);
        uint32_t* cnt   = (uint32_t*)(ws + OFF_CNT);
        uint32_t* offs  = (uint32_t*)(ws + OFF_OFFS);
        float*    prob  = (float*)(ws + OFF_PROB);
        uint32_t* epk   = (uint32_t*)(ws + OFF_EPK);
        ushort*   w1b   = (ushort*)(ws + OFF_W1B);
        ushort*   w2b   = (ushort*)(ws + OFF_W2B);

        hipLaunchKernelGGL(init_cnt, dim3(1), dim3(64), 0, stream, cnt);
        hipLaunchKernelGGL(gate_route, dim3(T_TOKENS / 4), dim3(256), 0, stream,
                           x, gw, gb, route, cnt, prob, epk);
        hipLaunchKernelGGL(prefix_offs, dim3(1), dim3(64), 0, stream, cnt, offs);
        hipLaunchKernelGGL(convert_x, dim3(T_TOKENS * DM / 1024), dim3(256), 0, stream, x, xb);
        // W1 transpose right before GEMM1 (w1b + xb stay L3-hot)
        hipLaunchKernelGGL((conv_transpose<DM, DF>), dim3((DM / 64) * (DF / 64), NEXP),
                           dim3(256), 0, stream, W1, w1b);
        hipLaunchKernelGGL((moe_gemm6<DM, DF, true, 1, 32>),
                           dim3(NEXP * 16 * 32, 1, 1), dim3(256), 0, stream,
                           xb, w1b, b1, route, cnt, offs, prob, h, (float*)nullptr);
        // W2 transpose right before GEMM2 (w2b + h stay L3-hot); yc aliases w1b
        hipLaunchKernelGGL((conv_transpose<DF, DM>), dim3((DF / 64) * (DM / 64), NEXP),
                           dim3(256), 0, stream, W2, w2b);
        hipLaunchKernelGGL((moe_gemm6<DF, DM, false, 4, 8>),
                           dim3(NEXP * 16 * 8, 1, 4), dim3(256), 0, stream,
                           h, w2b, (const float*)nullptr, route, cnt, offs,
                           (const float*)nullptr, (ushort*)nullptr, yc);
        hipLaunchKernelGGL(combine5, dim3(T_TOKENS * DM / 1024), dim3(256), 0, stream,
                           yc, epk, offs, prob, b2, out);
    } else {
        // ---- fallback: round-1 layout (~55 MB) ----
        const size_t F_XB = 0, F_H = 4194304, F_YC = 37748736;
        const size_t F_ROUTE = 54525952, F_CNT = 54591488, F_PROB = 54591552;
        ushort*   xb    = (ushort*)(ws + F_XB);
        ushort*   h     = (ushort*)(ws + F_H);
        float*    yc    = (float*)(ws + F_YC);
        uint32_t* route = (uint32_t*)(ws + F_ROUTE);
        uint32_t* cnt   = (uint32_t*)(ws + F_CNT);
        float*    prob  = (float*)(ws + F_PROB);
        uint32_t* epk   = (uint32_t*)(ws + F_PROB + 16384);

        hipLaunchKernelGGL(init_cnt, dim3(1), dim3(64), 0, stream, cnt);
        hipLaunchKernelGGL(gate_route, dim3(T_TOKENS / 4), dim3(256), 0, stream,
                           x, gw, gb, route, cnt, prob, epk);
        hipLaunchKernelGGL(convert_x, dim3(T_TOKENS * DM / 1024), dim3(256), 0, stream, x, xb);
        hipLaunchKernelGGL((moe_gemm_v1<DM, DF, true>), dim3(NEXP * 16, DF / 128),
                           dim3(256), 0, stream, xb, W1, b1, route, cnt, prob,
                           h, (float*)nullptr);
        hipLaunchKernelGGL((moe_gemm_v1<DF, DM, false>), dim3(NEXP * 16, DM / 128),
                           dim3(256), 0, stream, h, W2, b2, route, cnt, prob,
                           (ushort*)nullptr, yc);
        hipLaunchKernelGGL(combine1, dim3(T_TOKENS * DM / 1024), dim3(256), 0, stream, yc, out);
    }
}